// Round 1
// baseline (1041.211 us; speedup 1.0000x reference)
//
#include <hip/hip_runtime.h>

// ============================================================================
// CrossAttention fused pipeline, MI355X gfx950.  Round 6.
// - R6 change (single lever): attn pass-2 barrier no longer drains the
//   masked_out store queue.  Each kc issues 4 global_load_lds then 32
//   global_store_dword per lane; vmcnt is FIFO, so s_waitcnt vmcnt(32)
//   at the barrier completes the staging loads while the 32 newest ops
//   (this iteration's 512MB-aggregate masked writes) drain lazily under
//   the next iteration's compute.  __syncthreads (vmcnt(0)) was forcing
//   a full HBM write-queue drain 16x per block.
// - All K-loops single-ahead LDS double-buffered: sync -> stage(next) ->
//   compute(cur).
// - GEMM: BK=32 (m97/r4-proven inner structure), XOR LDS swizzle, dbuf.
// - Attention: two-pass recompute, dbuf K/V staging, wave-local Ps handoff
//   via s_waitcnt lgkmcnt(0) (r2-proven), 1 barrier per kc.
// - O-proj and fc2 outputs bf16 (saves 64 MB HBM traffic); LN reads bf16 Bv.
// ============================================================================

typedef unsigned short u16;
typedef __attribute__((ext_vector_type(8))) short  bf16x8;
typedef __attribute__((ext_vector_type(4))) float  f32x4;

#define GLL16(gp, lp) __builtin_amdgcn_global_load_lds(                     \
    (__attribute__((address_space(1))) const void*)(gp),                    \
    (__attribute__((address_space(3))) void*)(lp), 16, 0, 0)

__device__ __forceinline__ u16 f2bf(float x) {
  union { float f; unsigned u; } v; v.f = x;
  return (u16)((v.u + 0x7FFF + ((v.u >> 16) & 1)) >> 16);   // RNE
}
__device__ __forceinline__ float bf2f(u16 h) {
  union { unsigned u; float f; } v; v.u = ((unsigned)h) << 16;
  return v.f;
}
__device__ __forceinline__ f32x4 zero4() { f32x4 z = {0.f, 0.f, 0.f, 0.f}; return z; }

// ---------------------------------------------------------------------------
// Packing: activations (base,fusion) and 7 weights, fp32 -> bf16.
// ---------------------------------------------------------------------------
__global__ __launch_bounds__(256) void pack_act(const float* __restrict__ a,
                                                const float* __restrict__ b,
                                                u16* __restrict__ outa,
                                                u16* __restrict__ outb) {
  size_t i = (size_t)blockIdx.x * 256 + threadIdx.x;
  const float* in = blockIdx.y ? b : a;
  u16* out = blockIdx.y ? outb : outa;
  out[i] = f2bf(in[i]);
}

__global__ __launch_bounds__(256) void pack_w(
    const float* __restrict__ w0, const float* __restrict__ w1,
    const float* __restrict__ w2, const float* __restrict__ w3,
    const float* __restrict__ w4, const float* __restrict__ w5,
    const float* __restrict__ w6, u16* __restrict__ out) {
  size_t i = (size_t)blockIdx.x * 256 + threadIdx.x;
  const float* in;
  switch (blockIdx.y) {
    case 0: in = w0; break;  case 1: in = w1; break;
    case 2: in = w2; break;  case 3: in = w3; break;
    case 4: in = w4; break;  case 5: in = w5; break;
    default: in = w6; break;
  }
  out[(size_t)blockIdx.y * 1048576 + i] = f2bf(in[i]);
}

// ---------------------------------------------------------------------------
// GEMM: C[M,N] = A[M,K] @ W[N,K]^T, bf16, BK=32, double-buffered LDS.
// LDS row r holds 4x16B blocks; global block g stored at slot g ^ ((r>>1)&3).
// ---------------------------------------------------------------------------
#define EPI_QKV       0  // z=0: Q2 plain; z=1: K2 swizzled; z=2: Vt swizzled-T
#define EPI_BF16      1  // plain bf16 row-major
#define EPI_SILU_BF16 4  // silu(v+bias) -> bf16
#define EPI_BIAS_F32  6  // v+bias -> f32

template <int EPI>
__global__ __launch_bounds__(256) void gemm_bt(
    const u16* __restrict__ A, int lda,
    const u16* __restrict__ W, int ldw,
    int M, int N, int K,
    float* __restrict__ outF, u16* __restrict__ outU,
    const float* __restrict__ bias,
    const u16* __restrict__ A2) {
  __shared__ u16 As[2][128 * 32];   // 2 x 8 KB
  __shared__ u16 Bs[2][128 * 32];   // 2 x 8 KB
  int tid = threadIdx.x;
  int l = tid & 63, w = tid >> 6;
  int wr = w >> 1, wc = w & 1, lr = l & 15, lq = l >> 4;
  int m0 = blockIdx.y * 128, n0 = blockIdx.x * 128;

  const u16* Ap = A;
  const u16* Wp = W;
  u16* outUp = outU;
  if constexpr (EPI == EPI_QKV) {
    int z = blockIdx.z;
    if (z) Ap = A2;                      // K,V read fusion
    Wp = W + (size_t)z * 1048576;        // wq / wk / wv
    outUp = outU + (size_t)z * 8388608;  // Q2 / K2 / Vt
  }

  f32x4 acc[4][4];
#pragma unroll
  for (int i = 0; i < 4; i++)
#pragma unroll
    for (int j = 0; j < 4; j++) acc[i][j] = zero4();

  auto stage = [&](const u16* src, int ld, int r0, int k0, u16* lds) {
#pragma unroll
    for (int j = 0; j < 2; ++j) {
      int seg = j * 256 + tid;               // 512 segs x 16B
      int row = seg >> 2, sp = seg & 3;
      const u16* g = src + (size_t)(r0 + row) * ld + k0 +
                     ((sp ^ ((row >> 1) & 3)) << 3);
      GLL16(g, lds + seg * 8);               // lane-contiguous LDS dest
    }
  };

  int nk = K >> 5;
  stage(Ap, lda, m0, 0, As[0]);
  stage(Wp, ldw, n0, 0, Bs[0]);
  for (int kt = 0; kt < nk; ++kt) {
    __syncthreads();                          // drains stage(kt); prev reads done
    if (kt + 1 < nk) {                        // prefetch next tile (drained at
      stage(Ap, lda, m0, (kt + 1) << 5, As[(kt + 1) & 1]);   // NEXT sync, after
      stage(Wp, ldw, n0, (kt + 1) << 5, Bs[(kt + 1) & 1]);   // a full MFMA iter)
    }
    const u16* Ab = As[kt & 1];
    const u16* Bb = Bs[kt & 1];
    bf16x8 af[4], bw[4];
    int slot = (lq ^ ((lr >> 1) & 3)) << 3;
#pragma unroll
    for (int mi = 0; mi < 4; mi++)
      af[mi] = *(const bf16x8*)&Ab[(wr * 64 + mi * 16 + lr) * 32 + slot];
#pragma unroll
    for (int ni = 0; ni < 4; ni++)
      bw[ni] = *(const bf16x8*)&Bb[(wc * 64 + ni * 16 + lr) * 32 + slot];
#pragma unroll
    for (int mi = 0; mi < 4; mi++)
#pragma unroll
      for (int ni = 0; ni < 4; ni++)
        acc[mi][ni] = __builtin_amdgcn_mfma_f32_16x16x32_bf16(af[mi], bw[ni],
                                                              acc[mi][ni], 0, 0, 0);
  }

#pragma unroll
  for (int mi = 0; mi < 4; mi++) {
#pragma unroll
    for (int ni = 0; ni < 4; ni++) {
      int col = n0 + wc * 64 + ni * 16 + lr;
#pragma unroll
      for (int r = 0; r < 4; r++) {
        int row = m0 + wr * 64 + mi * 16 + lq * 4 + r;
        float v = acc[mi][ni][r];
        if constexpr (EPI == EPI_QKV) {
          int b = row >> 10, t = row & 1023, h = col >> 6, d = col & 63;
          int z = blockIdx.z;
          if (z == 0) {                       // Q2: [bh][t][64] plain
            outUp[((size_t)(b * 16 + h) * 1024 + t) * 64 + d] = f2bf(v);
          } else if (z == 1) {                // K2: XOR-(t&7) swizzled rows
            size_t base = ((size_t)(b * 16 + h) * 1024 + t) * 64;
            outUp[base + (((d >> 3) ^ (t & 7)) << 3) + (d & 7)] = f2bf(v);
          } else {                            // Vt: [bh][d][t], XOR-(d&7) per 64-chunk
            size_t o = ((size_t)(b * 16 + h) * 64 + d) * 1024 + (t & ~63) +
                       ((((t >> 3) & 7) ^ (d & 7)) << 3) + (t & 7);
            outUp[o] = f2bf(v);
          }
        } else if constexpr (EPI == EPI_BF16) {
          outUp[(size_t)row * N + col] = f2bf(v);
        } else if constexpr (EPI == EPI_SILU_BF16) {
          float z = v + bias[col];
          outUp[(size_t)row * N + col] = f2bf(z / (1.f + __expf(-z)));
        } else {  // EPI_BIAS_F32
          outF[(size_t)row * N + col] = v + bias[col];
        }
      }
    }
  }
}

// ---------------------------------------------------------------------------
// Attention: two-pass recompute, plain bf16, dbuf K/V staging.
// Block 256 thr (4 waves), 128 q-rows (32/wave).  Grid (8, 16, 8).
// Q2 [bh][t][64] plain; K2 [bh][t][64] XOR-(t&7); Vt [bh][d][1024] XOR-(d&7).
// ---------------------------------------------------------------------------
__global__ __launch_bounds__(256) void attn_kernel(
    const u16* __restrict__ Q2, const u16* __restrict__ K2,
    const u16* __restrict__ Vt, const float* __restrict__ alphap,
    float* __restrict__ masked_out, u16* __restrict__ attn_out) {
  __shared__ __align__(16) u16 Ks[2][4096];        // 16 KB
  __shared__ __align__(16) u16 Vs[2][4096];        // 16 KB
  __shared__ __align__(16) u16 Ps[4][2][16 * 72];  // 18 KB

  int tid = threadIdx.x;
  int l = tid & 63, w = tid >> 6, lr = l & 15, lq = l >> 4;
  int q0 = blockIdx.x * 128;
  int h = blockIdx.y, b = blockIdx.z;
  int bh = b * 16 + h;
  const u16* Qb = Q2 + (size_t)bh * 1024 * 64;
  const u16* Kb = K2 + (size_t)bh * 1024 * 64;
  const u16* Vb = Vt + (size_t)bh * 64 * 1024;
  float alpha = alphap[0];
  int qw = q0 + w * 32;

  auto stageK = [&](int kc, u16* dst) {
#pragma unroll
    for (int j = 0; j < 2; ++j) {
      int seg = j * 256 + tid;
      GLL16(Kb + (size_t)kc * 4096 + seg * 8, dst + seg * 8);
    }
  };
  auto stageV = [&](int kc, u16* dst) {
#pragma unroll
    for (int j = 0; j < 2; ++j) {
      int seg = j * 256 + tid;                  // row d = seg>>3, part = seg&7
      GLL16(Vb + (size_t)(seg >> 3) * 1024 + kc * 64 + (seg & 7) * 8, dst + seg * 8);
    }
  };

  // Q fragments in registers: [sub 16-rows][k-chunk]
  bf16x8 qf[2][2];
#pragma unroll
  for (int s = 0; s < 2; s++)
#pragma unroll
    for (int kt = 0; kt < 2; kt++)
      qf[s][kt] = *(const bf16x8*)(Qb + (size_t)(qw + s * 16 + lr) * 64 + kt * 32 + lq * 8);

  float s1[2][4] = {{0.f, 0.f, 0.f, 0.f}, {0.f, 0.f, 0.f, 0.f}};

  // ---- pass 1 ----
  stageK(0, Ks[0]);
  for (int kc = 0; kc < 16; ++kc) {
    __syncthreads();                            // drains stage(kc); prev reads done
    if (kc + 1 < 16) stageK(kc + 1, Ks[(kc + 1) & 1]);
    const u16* Kc = Ks[kc & 1];
    f32x4 acc[2][4];
#pragma unroll
    for (int s = 0; s < 2; s++)
#pragma unroll
      for (int ni = 0; ni < 4; ni++) acc[s][ni] = zero4();
#pragma unroll
    for (int ni = 0; ni < 4; ++ni) {
      int t = ni * 16 + lr;
      bf16x8 k0 = *(const bf16x8*)&Kc[t * 64 + (((0 + lq) ^ (lr & 7)) << 3)];
      bf16x8 k1 = *(const bf16x8*)&Kc[t * 64 + (((4 + lq) ^ (lr & 7)) << 3)];
#pragma unroll
      for (int s = 0; s < 2; s++) {
        acc[s][ni] = __builtin_amdgcn_mfma_f32_16x16x32_bf16(qf[s][0], k0, acc[s][ni], 0, 0, 0);
        acc[s][ni] = __builtin_amdgcn_mfma_f32_16x16x32_bf16(qf[s][1], k1, acc[s][ni], 0, 0, 0);
      }
    }
#pragma unroll
    for (int s = 0; s < 2; s++)
#pragma unroll
      for (int ni = 0; ni < 4; ni++)
#pragma unroll
        for (int r = 0; r < 4; r++)
          s1[s][r] += __expf(acc[s][ni][r] * 0.125f);
  }
#pragma unroll
  for (int s = 0; s < 2; s++)
#pragma unroll
    for (int r = 0; r < 4; r++) {
      float v = s1[s][r];
      v += __shfl_xor(v, 1); v += __shfl_xor(v, 2);
      v += __shfl_xor(v, 4); v += __shfl_xor(v, 8);
      s1[s][r] = 1.0f / v;
    }

  // ---- pass 2 ----
  float s2[2][4] = {{0.f, 0.f, 0.f, 0.f}, {0.f, 0.f, 0.f, 0.f}};
  f32x4 oacc[2][4];
#pragma unroll
  for (int s = 0; s < 2; s++)
#pragma unroll
    for (int dg = 0; dg < 4; dg++) oacc[s][dg] = zero4();

  stageK(0, Ks[0]);                             // Ks[0] reads drained at kc=15 sync
  stageV(0, Vs[0]);
  for (int kc = 0; kc < 16; ++kc) {
    // R6: counted-vmcnt barrier.  VMEM issue order per iteration is
    // [4x global_load_lds (stage kc)] then [32x global_store_dword
    // (masked_out)].  vmcnt is FIFO: waiting to <=32 outstanding
    // completes the staging loads (and all older stores) while this
    // iteration's 32 masked stores keep draining under the next
    // iteration's compute.  lgkmcnt(0) ensures our ds_reads of the
    // buffer being overwritten next are complete before the barrier.
    if (kc == 0) {
      asm volatile("s_waitcnt vmcnt(0) lgkmcnt(0)" ::: "memory");
    } else {
      asm volatile("s_waitcnt vmcnt(32) lgkmcnt(0)" ::: "memory");
    }
    __builtin_amdgcn_s_barrier();
    __builtin_amdgcn_sched_barrier(0);
    if (kc + 1 < 16) {
      stageK(kc + 1, Ks[(kc + 1) & 1]);
      stageV(kc + 1, Vs[(kc + 1) & 1]);
    }
    const u16* Kc = Ks[kc & 1];
    const u16* Vc = Vs[kc & 1];

    f32x4 acc[2][4];
#pragma unroll
    for (int s = 0; s < 2; s++)
#pragma unroll
      for (int ni = 0; ni < 4; ni++) acc[s][ni] = zero4();
#pragma unroll
    for (int ni = 0; ni < 4; ++ni) {
      int t = ni * 16 + lr;
      bf16x8 k0 = *(const bf16x8*)&Kc[t * 64 + (((0 + lq) ^ (lr & 7)) << 3)];
      bf16x8 k1 = *(const bf16x8*)&Kc[t * 64 + (((4 + lq) ^ (lr & 7)) << 3)];
#pragma unroll
      for (int s = 0; s < 2; s++) {
        acc[s][ni] = __builtin_amdgcn_mfma_f32_16x16x32_bf16(qf[s][0], k0, acc[s][ni], 0, 0, 0);
        acc[s][ni] = __builtin_amdgcn_mfma_f32_16x16x32_bf16(qf[s][1], k1, acc[s][ni], 0, 0, 0);
      }
    }

#pragma unroll
    for (int s = 0; s < 2; s++) {
#pragma unroll
      for (int ni = 0; ni < 4; ni++) {
#pragma unroll
        for (int r = 0; r < 4; r++) {
          float e = __expf(acc[s][ni][r] * 0.125f);
          float a = e * s1[s][r];
          a = (a >= alpha) ? a : 0.0f;
          size_t row = (size_t)bh * 1024 + qw + s * 16 + lq * 4 + r;
          masked_out[row * 1024 + kc * 64 + ni * 16 + lr] = a;
          float p = __expf(a);
          s2[s][r] += p;
          Ps[w][s][(lq * 4 + r) * 72 + ni * 16 + lr] = f2bf(p);
        }
      }
    }
    // wave-local Ps handoff: Ps[w] is written and read only by wave w.
    // r2-proven: all outstanding DS ops complete before the reads below.
    asm volatile("s_waitcnt lgkmcnt(0)" ::: "memory");

    bf16x8 pf[2][2];
#pragma unroll
    for (int s = 0; s < 2; s++)
#pragma unroll
      for (int kt = 0; kt < 2; kt++)
        pf[s][kt] = *(const bf16x8*)&Ps[w][s][lr * 72 + kt * 32 + lq * 8];
#pragma unroll
    for (int dg = 0; dg < 4; dg++) {
      int d = dg * 16 + lr;
      bf16x8 v0 = *(const bf16x8*)&Vc[d * 64 + (((0 + lq) ^ (lr & 7)) << 3)];
      bf16x8 v1 = *(const bf16x8*)&Vc[d * 64 + (((4 + lq) ^ (lr & 7)) << 3)];
#pragma unroll
      for (int s = 0; s < 2; s++) {
        oacc[s][dg] = __builtin_amdgcn_mfma_f32_16x16x32_bf16(pf[s][0], v0, oacc[s][dg], 0, 0, 0);
        oacc[s][dg] = __builtin_amdgcn_mfma_f32_16x16x32_bf16(pf[s][1], v1, oacc[s][dg], 0, 0, 0);
      }
    }
  }

#pragma unroll
  for (int s = 0; s < 2; s++)
#pragma unroll
    for (int r = 0; r < 4; r++) {
      float v = s2[s][r];
      v += __shfl_xor(v, 1); v += __shfl_xor(v, 2);
      v += __shfl_xor(v, 4); v += __shfl_xor(v, 8);
      s2[s][r] = 1.0f / v;
    }
#pragma unroll
  for (int s = 0; s < 2; s++)
#pragma unroll
    for (int dg = 0; dg < 4; dg++)
#pragma unroll
      for (int r = 0; r < 4; r++) {
        int q = qw + s * 16 + lq * 4 + r;
        attn_out[(size_t)(b * 1024 + q) * 1024 + h * 64 + dg * 16 + lr] =
            f2bf(oacc[s][dg][r] * s2[s][r]);
      }
}

// ---------------------------------------------------------------------------
// LayerNorm over D=1024: y = (A + bf2f(Bv) - mu)*rsqrt(var+eps)*g + beta
// ---------------------------------------------------------------------------
__global__ __launch_bounds__(256) void ln_kernel(
    const float* __restrict__ A, const u16* __restrict__ Bv,
    const float* __restrict__ g, const float* __restrict__ beta,
    float* __restrict__ outF, u16* __restrict__ outB) {
  __shared__ float red[4];
  int row = blockIdx.x, t = threadIdx.x;
  const float* pa = A + (size_t)row * 1024;
  const u16* pb = Bv + (size_t)row * 1024;
  float v[4];
  float s = 0.f;
#pragma unroll
  for (int i = 0; i < 4; i++) {
    int c = t + 256 * i;
    v[i] = pa[c] + bf2f(pb[c]);
    s += v[i];
  }
#pragma unroll
  for (int off = 1; off < 64; off <<= 1) s += __shfl_xor(s, off);
  if ((t & 63) == 0) red[t >> 6] = s;
  __syncthreads();
  s = red[0] + red[1] + red[2] + red[3];
  float mu = s * 0.0009765625f;
  float q = 0.f;
#pragma unroll
  for (int i = 0; i < 4; i++) { float d = v[i] - mu; q += d * d; }
  __syncthreads();
#pragma unroll
  for (int off = 1; off < 64; off <<= 1) q += __shfl_xor(q, off);
  if ((t & 63) == 0) red[t >> 6] = q;
  __syncthreads();
  q = red[0] + red[1] + red[2] + red[3];
  float rs = rsqrtf(q * 0.0009765625f + 1e-5f);
#pragma unroll
  for (int i = 0; i < 4; i++) {
    int c = t + 256 * i;
    float y = (v[i] - mu) * rs * g[c] + beta[c];
    if (outF) outF[(size_t)row * 1024 + c] = y;
    if (outB) outB[(size_t)row * 1024 + c] = f2bf(y);
  }
}

// ---------------------------------------------------------------------------
// Workspace (bytes), aliased by lifetime.  Total 148,897,792 + 33 MB.
// ---------------------------------------------------------------------------
#define WS_BASEB   0            // [8192][1024] u16 = 16 MB (dead after QKV gemm)
#define WS_FUSB    16777216     // 16 MB (dead after QKV gemm)
#define WS_W       33554432     // 7 x [1024][1024] u16 = 14 MB
#define WS_QKV     48234496     // Q2 16MB | K2 16MB | Vt 16MB (dead after attn)
#define WS_ATTNO   98566144     // [8192][1024] u16 = 16 MB (dead after O gemm)
#define WS_X       115343360    // [8192][1024] f32 = 32 MB (ends 148897792)
#define WS_OB      WS_FUSB                  // [8192][1024] u16 (fusb dead)
#define WS_XB      WS_BASEB                 // [8192][1024] u16 (baseb dead)
#define WS_H1      WS_ATTNO                 // alias (attno dead)
#define WS_FFB     WS_QKV                   // alias Q2 (dead after attn)
#define WS_YB      (WS_QKV + 16777216)      // alias K2 (dead)

extern "C" void kernel_launch(void* const* d_in, const int* in_sizes, int n_in,
                              void* d_out, int out_size, void* d_ws, size_t ws_size,
                              hipStream_t stream) {
  const float* base   = (const float*)d_in[0];
  const float* fusion = (const float*)d_in[1];
  const float* Wq     = (const float*)d_in[2];
  const float* Wk     = (const float*)d_in[3];
  const float* Wv     = (const float*)d_in[4];
  const float* Wo     = (const float*)d_in[5];
  const float* g1     = (const float*)d_in[6];
  const float* b1     = (const float*)d_in[7];
  const float* g2     = (const float*)d_in[8];
  const float* b2     = (const float*)d_in[9];
  const float* fc1w   = (const float*)d_in[10];
  const float* fc1b   = (const float*)d_in[11];
  const float* fc2w   = (const float*)d_in[12];
  const float* fc2b   = (const float*)d_in[13];
  const float* rw     = (const float*)d_in[14];
  const float* rb     = (const float*)d_in[15];
  const float* alphap = (const float*)d_in[16];

  char* ws = (char*)d_ws;
  u16* baseb  = (u16*)(ws + WS_BASEB);
  u16* fusb   = (u16*)(ws + WS_FUSB);
  u16* wall   = (u16*)(ws + WS_W);        // wq|wk|wv|wo|fc1|fc2|rw
  u16* Q2     = (u16*)(ws + WS_QKV);      // K2 = Q2+8388608, Vt = Q2+16777216 (elems)
  u16* attno  = (u16*)(ws + WS_ATTNO);
  u16* obufb  = (u16*)(ws + WS_OB);
  float* x    = (float*)(ws + WS_X);
  u16* xb     = (u16*)(ws + WS_XB);
  u16* h1     = (u16*)(ws + WS_H1);
  u16* ffb    = (u16*)(ws + WS_FFB);
  u16* yb     = (u16*)(ws + WS_YB);

  float* final_out  = (float*)d_out;
  float* masked_out = final_out + 8388608;

  // 1. pack
  pack_act<<<dim3(32768, 2), 256, 0, stream>>>(base, fusion, baseb, fusb);
  pack_w<<<dim3(4096, 7), 256, 0, stream>>>(Wq, Wk, Wv, Wo, fc1w, fc2w, rw, wall);

  dim3 gg(8, 64);

  // 2. QKV merged (z: 0=Q plain, 1=K swizzled, 2=Vt)
  gemm_bt<EPI_QKV><<<dim3(8, 64, 3), 256, 0, stream>>>(
      baseb, 1024, wall, 1024, 8192, 1024, 1024, nullptr, Q2, nullptr, fusb);

  // 3. attention
  attn_kernel<<<dim3(8, 16, 8), 256, 0, stream>>>(
      Q2, Q2 + 8388608, Q2 + 16777216, alphap, masked_out, attno);

  // 4. output proj (bf16 out) + LN1
  gemm_bt<EPI_BF16><<<gg, 256, 0, stream>>>(attno, 1024, wall + 3 * 1048576, 1024,
                                            8192, 1024, 1024, nullptr, obufb, nullptr, nullptr);
  ln_kernel<<<8192, 256, 0, stream>>>(base, obufb, g1, b1, x, xb);

  // 5. FFN + LN2
  gemm_bt<EPI_SILU_BF16><<<gg, 256, 0, stream>>>(xb, 1024, wall + 4 * 1048576, 1024,
                                                 8192, 1024, 1024, nullptr, h1, fc1b, nullptr);
  gemm_bt<EPI_SILU_BF16><<<gg, 256, 0, stream>>>(h1, 1024, wall + 5 * 1048576, 1024,
                                                 8192, 1024, 1024, nullptr, ffb, fc2b, nullptr);
  ln_kernel<<<8192, 256, 0, stream>>>(x, ffb, g2, b2, nullptr, yb);

  // 6. final projection
  gemm_bt<EPI_BIAS_F32><<<gg, 256, 0, stream>>>(yb, 1024, wall + 6 * 1048576, 1024,
                                                8192, 1024, 1024, final_out, nullptr, rb, nullptr);
}

// Round 2
// 990.881 us; speedup vs baseline: 1.0508x; 1.0508x over previous
//
#include <hip/hip_runtime.h>

// ============================================================================
// CrossAttention fused pipeline, MI355X gfx950.  Round 7.
// - R7 levers (locality + wave-arbitration, all catalog-proven mechanisms):
//   1. attn grid XCD-swizzle: all 8 q-blocks of one bh -> same XCD, so K/V
//      (256 KB/bh, read 3x) are served from that XCD's 4MB L2 (T1, m192).
//   2. GEMM grid XCD-swizzle (chunked): each XCD gets 8 contiguous m-panels
//      (2 MB A) + full W (2 MB) = its exact L2 capacity (T1).
//   3. s_setprio(1) around attn MFMA clusters (T5: +4-7% on attn, m191;
//      NOT applied to GEMM - null on lockstep structures, m190).
//   4. pack kernels vectorized f32x4 -> short4 (G13).
// - R6 counted-vmcnt in attn pass-2 kept (neutral, harmless).
// - GEMM: BK=32 m97-structure, XOR LDS swizzle, dbuf.
// - Attention: two-pass recompute, dbuf K/V staging, wave-local Ps handoff.
// ============================================================================

typedef unsigned short u16;
typedef __attribute__((ext_vector_type(8))) short  bf16x8;
typedef __attribute__((ext_vector_type(4))) short  s16x4;
typedef __attribute__((ext_vector_type(4))) float  f32x4;

#define GLL16(gp, lp) __builtin_amdgcn_global_load_lds(                     \
    (__attribute__((address_space(1))) const void*)(gp),                    \
    (__attribute__((address_space(3))) void*)(lp), 16, 0, 0)

__device__ __forceinline__ u16 f2bf(float x) {
  union { float f; unsigned u; } v; v.f = x;
  return (u16)((v.u + 0x7FFF + ((v.u >> 16) & 1)) >> 16);   // RNE
}
__device__ __forceinline__ float bf2f(u16 h) {
  union { unsigned u; float f; } v; v.u = ((unsigned)h) << 16;
  return v.f;
}
__device__ __forceinline__ f32x4 zero4() { f32x4 z = {0.f, 0.f, 0.f, 0.f}; return z; }

// ---------------------------------------------------------------------------
// Packing: activations (base,fusion) and 7 weights, fp32 -> bf16, x4 vector.
// ---------------------------------------------------------------------------
__global__ __launch_bounds__(256) void pack_act(const float* __restrict__ a,
                                                const float* __restrict__ b,
                                                u16* __restrict__ outa,
                                                u16* __restrict__ outb) {
  size_t i = (size_t)blockIdx.x * 256 + threadIdx.x;        // vec4 index
  const f32x4* in = (const f32x4*)(blockIdx.y ? b : a);
  s16x4* out = (s16x4*)(blockIdx.y ? outb : outa);
  f32x4 v = in[i];
  s16x4 o;
  o[0] = (short)f2bf(v[0]); o[1] = (short)f2bf(v[1]);
  o[2] = (short)f2bf(v[2]); o[3] = (short)f2bf(v[3]);
  out[i] = o;
}

__global__ __launch_bounds__(256) void pack_w(
    const float* __restrict__ w0, const float* __restrict__ w1,
    const float* __restrict__ w2, const float* __restrict__ w3,
    const float* __restrict__ w4, const float* __restrict__ w5,
    const float* __restrict__ w6, u16* __restrict__ out) {
  size_t i = (size_t)blockIdx.x * 256 + threadIdx.x;        // vec4 index
  const float* in;
  switch (blockIdx.y) {
    case 0: in = w0; break;  case 1: in = w1; break;
    case 2: in = w2; break;  case 3: in = w3; break;
    case 4: in = w4; break;  case 5: in = w5; break;
    default: in = w6; break;
  }
  f32x4 v = ((const f32x4*)in)[i];
  s16x4 o;
  o[0] = (short)f2bf(v[0]); o[1] = (short)f2bf(v[1]);
  o[2] = (short)f2bf(v[2]); o[3] = (short)f2bf(v[3]);
  ((s16x4*)(out + (size_t)blockIdx.y * 1048576))[i] = o;
}

// ---------------------------------------------------------------------------
// GEMM: C[M,N] = A[M,K] @ W[N,K]^T, bf16, BK=32, double-buffered LDS.
// LDS row r holds 4x16B blocks; global block g stored at slot g ^ ((r>>1)&3).
// ---------------------------------------------------------------------------
#define EPI_QKV       0  // z=0: Q2 plain; z=1: K2 swizzled; z=2: Vt swizzled-T
#define EPI_BF16      1  // plain bf16 row-major
#define EPI_SILU_BF16 4  // silu(v+bias) -> bf16
#define EPI_BIAS_F32  6  // v+bias -> f32

template <int EPI>
__global__ __launch_bounds__(256) void gemm_bt(
    const u16* __restrict__ A, int lda,
    const u16* __restrict__ W, int ldw,
    int M, int N, int K,
    float* __restrict__ outF, u16* __restrict__ outU,
    const float* __restrict__ bias,
    const u16* __restrict__ A2) {
  __shared__ u16 As[2][128 * 32];   // 2 x 8 KB
  __shared__ u16 Bs[2][128 * 32];   // 2 x 8 KB
  int tid = threadIdx.x;
  int l = tid & 63, w = tid >> 6;
  int wr = w >> 1, wc = w & 1, lr = l & 15, lq = l >> 4;

  // R7: XCD-chunked swizzle.  HW assigns XCD = dispatch_id % 8; give each
  // XCD 64 consecutive logical blocks = 8 m-panels (2MB A) + all n (2MB W),
  // exactly its 4MB L2.  512 % 8 == 0 -> bijective.
  int fid = blockIdx.y * 8 + blockIdx.x;        // dispatch order, x fastest
  int swz = (fid & 7) * 64 + (fid >> 3);
  int m0 = (swz >> 3) * 128, n0 = (swz & 7) * 128;

  const u16* Ap = A;
  const u16* Wp = W;
  u16* outUp = outU;
  if constexpr (EPI == EPI_QKV) {
    int z = blockIdx.z;
    if (z) Ap = A2;                      // K,V read fusion
    Wp = W + (size_t)z * 1048576;        // wq / wk / wv
    outUp = outU + (size_t)z * 8388608;  // Q2 / K2 / Vt
  }

  f32x4 acc[4][4];
#pragma unroll
  for (int i = 0; i < 4; i++)
#pragma unroll
    for (int j = 0; j < 4; j++) acc[i][j] = zero4();

  auto stage = [&](const u16* src, int ld, int r0, int k0, u16* lds) {
#pragma unroll
    for (int j = 0; j < 2; ++j) {
      int seg = j * 256 + tid;               // 512 segs x 16B
      int row = seg >> 2, sp = seg & 3;
      const u16* g = src + (size_t)(r0 + row) * ld + k0 +
                     ((sp ^ ((row >> 1) & 3)) << 3);
      GLL16(g, lds + seg * 8);               // lane-contiguous LDS dest
    }
  };

  int nk = K >> 5;
  stage(Ap, lda, m0, 0, As[0]);
  stage(Wp, ldw, n0, 0, Bs[0]);
  for (int kt = 0; kt < nk; ++kt) {
    __syncthreads();                          // drains stage(kt); prev reads done
    if (kt + 1 < nk) {                        // prefetch next tile (drained at
      stage(Ap, lda, m0, (kt + 1) << 5, As[(kt + 1) & 1]);   // NEXT sync, after
      stage(Wp, ldw, n0, (kt + 1) << 5, Bs[(kt + 1) & 1]);   // a full MFMA iter)
    }
    const u16* Ab = As[kt & 1];
    const u16* Bb = Bs[kt & 1];
    bf16x8 af[4], bw[4];
    int slot = (lq ^ ((lr >> 1) & 3)) << 3;
#pragma unroll
    for (int mi = 0; mi < 4; mi++)
      af[mi] = *(const bf16x8*)&Ab[(wr * 64 + mi * 16 + lr) * 32 + slot];
#pragma unroll
    for (int ni = 0; ni < 4; ni++)
      bw[ni] = *(const bf16x8*)&Bb[(wc * 64 + ni * 16 + lr) * 32 + slot];
#pragma unroll
    for (int mi = 0; mi < 4; mi++)
#pragma unroll
      for (int ni = 0; ni < 4; ni++)
        acc[mi][ni] = __builtin_amdgcn_mfma_f32_16x16x32_bf16(af[mi], bw[ni],
                                                              acc[mi][ni], 0, 0, 0);
  }

#pragma unroll
  for (int mi = 0; mi < 4; mi++) {
#pragma unroll
    for (int ni = 0; ni < 4; ni++) {
      int col = n0 + wc * 64 + ni * 16 + lr;
#pragma unroll
      for (int r = 0; r < 4; r++) {
        int row = m0 + wr * 64 + mi * 16 + lq * 4 + r;
        float v = acc[mi][ni][r];
        if constexpr (EPI == EPI_QKV) {
          int b = row >> 10, t = row & 1023, h = col >> 6, d = col & 63;
          int z = blockIdx.z;
          if (z == 0) {                       // Q2: [bh][t][64] plain
            outUp[((size_t)(b * 16 + h) * 1024 + t) * 64 + d] = f2bf(v);
          } else if (z == 1) {                // K2: XOR-(t&7) swizzled rows
            size_t base = ((size_t)(b * 16 + h) * 1024 + t) * 64;
            outUp[base + (((d >> 3) ^ (t & 7)) << 3) + (d & 7)] = f2bf(v);
          } else {                            // Vt: [bh][d][t], XOR-(d&7) per 64-chunk
            size_t o = ((size_t)(b * 16 + h) * 64 + d) * 1024 + (t & ~63) +
                       ((((t >> 3) & 7) ^ (d & 7)) << 3) + (t & 7);
            outUp[o] = f2bf(v);
          }
        } else if constexpr (EPI == EPI_BF16) {
          outUp[(size_t)row * N + col] = f2bf(v);
        } else if constexpr (EPI == EPI_SILU_BF16) {
          float z = v + bias[col];
          outUp[(size_t)row * N + col] = f2bf(z / (1.f + __expf(-z)));
        } else {  // EPI_BIAS_F32
          outF[(size_t)row * N + col] = v + bias[col];
        }
      }
    }
  }
}

// ---------------------------------------------------------------------------
// Attention: two-pass recompute, plain bf16, dbuf K/V staging.
// Block 256 thr (4 waves), 128 q-rows (32/wave).  Grid (1024).
// R7 swizzle: qi = bid>>7, bh = (bid&7)*16 + ((bid>>3)&15) -> all 8 q-chunks
// of one bh share an XCD (K/V 256KB/bh served from that XCD's L2).
// Q2 [bh][t][64] plain; K2 [bh][t][64] XOR-(t&7); Vt [bh][d][1024] XOR-(d&7).
// ---------------------------------------------------------------------------
__global__ __launch_bounds__(256) void attn_kernel(
    const u16* __restrict__ Q2, const u16* __restrict__ K2,
    const u16* __restrict__ Vt, const float* __restrict__ alphap,
    float* __restrict__ masked_out, u16* __restrict__ attn_out) {
  __shared__ __align__(16) u16 Ks[2][4096];        // 16 KB
  __shared__ __align__(16) u16 Vs[2][4096];        // 16 KB
  __shared__ __align__(16) u16 Ps[4][2][16 * 72];  // 18 KB

  int tid = threadIdx.x;
  int l = tid & 63, w = tid >> 6, lr = l & 15, lq = l >> 4;

  int bid = blockIdx.x;
  int qi  = bid >> 7;                              // 0..7 q-chunk
  int bh  = (bid & 7) * 16 + ((bid >> 3) & 15);    // 0..127, XCD-resident
  int h = bh & 15, b = bh >> 4;
  int q0 = qi * 128;

  const u16* Qb = Q2 + (size_t)bh * 1024 * 64;
  const u16* Kb = K2 + (size_t)bh * 1024 * 64;
  const u16* Vb = Vt + (size_t)bh * 64 * 1024;
  float alpha = alphap[0];
  int qw = q0 + w * 32;

  auto stageK = [&](int kc, u16* dst) {
#pragma unroll
    for (int j = 0; j < 2; ++j) {
      int seg = j * 256 + tid;
      GLL16(Kb + (size_t)kc * 4096 + seg * 8, dst + seg * 8);
    }
  };
  auto stageV = [&](int kc, u16* dst) {
#pragma unroll
    for (int j = 0; j < 2; ++j) {
      int seg = j * 256 + tid;                  // row d = seg>>3, part = seg&7
      GLL16(Vb + (size_t)(seg >> 3) * 1024 + kc * 64 + (seg & 7) * 8, dst + seg * 8);
    }
  };

  // Q fragments in registers: [sub 16-rows][k-chunk]
  bf16x8 qf[2][2];
#pragma unroll
  for (int s = 0; s < 2; s++)
#pragma unroll
    for (int kt = 0; kt < 2; kt++)
      qf[s][kt] = *(const bf16x8*)(Qb + (size_t)(qw + s * 16 + lr) * 64 + kt * 32 + lq * 8);

  float s1[2][4] = {{0.f, 0.f, 0.f, 0.f}, {0.f, 0.f, 0.f, 0.f}};

  // ---- pass 1 ----
  stageK(0, Ks[0]);
  for (int kc = 0; kc < 16; ++kc) {
    __syncthreads();                            // drains stage(kc); prev reads done
    if (kc + 1 < 16) stageK(kc + 1, Ks[(kc + 1) & 1]);
    const u16* Kc = Ks[kc & 1];
    f32x4 acc[2][4];
#pragma unroll
    for (int s = 0; s < 2; s++)
#pragma unroll
      for (int ni = 0; ni < 4; ni++) acc[s][ni] = zero4();
    __builtin_amdgcn_s_setprio(1);              // T5: favor MFMA wave (m191)
#pragma unroll
    for (int ni = 0; ni < 4; ++ni) {
      int t = ni * 16 + lr;
      bf16x8 k0 = *(const bf16x8*)&Kc[t * 64 + (((0 + lq) ^ (lr & 7)) << 3)];
      bf16x8 k1 = *(const bf16x8*)&Kc[t * 64 + (((4 + lq) ^ (lr & 7)) << 3)];
#pragma unroll
      for (int s = 0; s < 2; s++) {
        acc[s][ni] = __builtin_amdgcn_mfma_f32_16x16x32_bf16(qf[s][0], k0, acc[s][ni], 0, 0, 0);
        acc[s][ni] = __builtin_amdgcn_mfma_f32_16x16x32_bf16(qf[s][1], k1, acc[s][ni], 0, 0, 0);
      }
    }
    __builtin_amdgcn_s_setprio(0);
#pragma unroll
    for (int s = 0; s < 2; s++)
#pragma unroll
      for (int ni = 0; ni < 4; ni++)
#pragma unroll
        for (int r = 0; r < 4; r++)
          s1[s][r] += __expf(acc[s][ni][r] * 0.125f);
  }
#pragma unroll
  for (int s = 0; s < 2; s++)
#pragma unroll
    for (int r = 0; r < 4; r++) {
      float v = s1[s][r];
      v += __shfl_xor(v, 1); v += __shfl_xor(v, 2);
      v += __shfl_xor(v, 4); v += __shfl_xor(v, 8);
      s1[s][r] = 1.0f / v;
    }

  // ---- pass 2 ----
  float s2[2][4] = {{0.f, 0.f, 0.f, 0.f}, {0.f, 0.f, 0.f, 0.f}};
  f32x4 oacc[2][4];
#pragma unroll
  for (int s = 0; s < 2; s++)
#pragma unroll
    for (int dg = 0; dg < 4; dg++) oacc[s][dg] = zero4();

  stageK(0, Ks[0]);                             // Ks[0] reads drained at kc=15 sync
  stageV(0, Vs[0]);
  for (int kc = 0; kc < 16; ++kc) {
    // counted-vmcnt barrier (R6): staging loads complete, masked stores
    // drain lazily under next iteration's compute.
    if (kc == 0) {
      asm volatile("s_waitcnt vmcnt(0) lgkmcnt(0)" ::: "memory");
    } else {
      asm volatile("s_waitcnt vmcnt(32) lgkmcnt(0)" ::: "memory");
    }
    __builtin_amdgcn_s_barrier();
    __builtin_amdgcn_sched_barrier(0);
    if (kc + 1 < 16) {
      stageK(kc + 1, Ks[(kc + 1) & 1]);
      stageV(kc + 1, Vs[(kc + 1) & 1]);
    }
    const u16* Kc = Ks[kc & 1];
    const u16* Vc = Vs[kc & 1];

    f32x4 acc[2][4];
#pragma unroll
    for (int s = 0; s < 2; s++)
#pragma unroll
      for (int ni = 0; ni < 4; ni++) acc[s][ni] = zero4();
    __builtin_amdgcn_s_setprio(1);              // T5
#pragma unroll
    for (int ni = 0; ni < 4; ++ni) {
      int t = ni * 16 + lr;
      bf16x8 k0 = *(const bf16x8*)&Kc[t * 64 + (((0 + lq) ^ (lr & 7)) << 3)];
      bf16x8 k1 = *(const bf16x8*)&Kc[t * 64 + (((4 + lq) ^ (lr & 7)) << 3)];
#pragma unroll
      for (int s = 0; s < 2; s++) {
        acc[s][ni] = __builtin_amdgcn_mfma_f32_16x16x32_bf16(qf[s][0], k0, acc[s][ni], 0, 0, 0);
        acc[s][ni] = __builtin_amdgcn_mfma_f32_16x16x32_bf16(qf[s][1], k1, acc[s][ni], 0, 0, 0);
      }
    }
    __builtin_amdgcn_s_setprio(0);

#pragma unroll
    for (int s = 0; s < 2; s++) {
#pragma unroll
      for (int ni = 0; ni < 4; ni++) {
#pragma unroll
        for (int r = 0; r < 4; r++) {
          float e = __expf(acc[s][ni][r] * 0.125f);
          float a = e * s1[s][r];
          a = (a >= alpha) ? a : 0.0f;
          size_t row = (size_t)bh * 1024 + qw + s * 16 + lq * 4 + r;
          masked_out[row * 1024 + kc * 64 + ni * 16 + lr] = a;
          float p = __expf(a);
          s2[s][r] += p;
          Ps[w][s][(lq * 4 + r) * 72 + ni * 16 + lr] = f2bf(p);
        }
      }
    }
    // wave-local Ps handoff: Ps[w] is written and read only by wave w.
    asm volatile("s_waitcnt lgkmcnt(0)" ::: "memory");

    bf16x8 pf[2][2];
#pragma unroll
    for (int s = 0; s < 2; s++)
#pragma unroll
      for (int kt = 0; kt < 2; kt++)
        pf[s][kt] = *(const bf16x8*)&Ps[w][s][lr * 72 + kt * 32 + lq * 8];
    __builtin_amdgcn_s_setprio(1);              // T5
#pragma unroll
    for (int dg = 0; dg < 4; dg++) {
      int d = dg * 16 + lr;
      bf16x8 v0 = *(const bf16x8*)&Vc[d * 64 + (((0 + lq) ^ (lr & 7)) << 3)];
      bf16x8 v1 = *(const bf16x8*)&Vc[d * 64 + (((4 + lq) ^ (lr & 7)) << 3)];
#pragma unroll
      for (int s = 0; s < 2; s++) {
        oacc[s][dg] = __builtin_amdgcn_mfma_f32_16x16x32_bf16(pf[s][0], v0, oacc[s][dg], 0, 0, 0);
        oacc[s][dg] = __builtin_amdgcn_mfma_f32_16x16x32_bf16(pf[s][1], v1, oacc[s][dg], 0, 0, 0);
      }
    }
    __builtin_amdgcn_s_setprio(0);
  }

#pragma unroll
  for (int s = 0; s < 2; s++)
#pragma unroll
    for (int r = 0; r < 4; r++) {
      float v = s2[s][r];
      v += __shfl_xor(v, 1); v += __shfl_xor(v, 2);
      v += __shfl_xor(v, 4); v += __shfl_xor(v, 8);
      s2[s][r] = 1.0f / v;
    }
#pragma unroll
  for (int s = 0; s < 2; s++)
#pragma unroll
    for (int dg = 0; dg < 4; dg++)
#pragma unroll
      for (int r = 0; r < 4; r++) {
        int q = qw + s * 16 + lq * 4 + r;
        attn_out[(size_t)(b * 1024 + q) * 1024 + h * 64 + dg * 16 + lr] =
            f2bf(oacc[s][dg][r] * s2[s][r]);
      }
}

// ---------------------------------------------------------------------------
// LayerNorm over D=1024: y = (A + bf2f(Bv) - mu)*rsqrt(var+eps)*g + beta
// ---------------------------------------------------------------------------
__global__ __launch_bounds__(256) void ln_kernel(
    const float* __restrict__ A, const u16* __restrict__ Bv,
    const float* __restrict__ g, const float* __restrict__ beta,
    float* __restrict__ outF, u16* __restrict__ outB) {
  __shared__ float red[4];
  int row = blockIdx.x, t = threadIdx.x;
  const float* pa = A + (size_t)row * 1024;
  const u16* pb = Bv + (size_t)row * 1024;
  float v[4];
  float s = 0.f;
#pragma unroll
  for (int i = 0; i < 4; i++) {
    int c = t + 256 * i;
    v[i] = pa[c] + bf2f(pb[c]);
    s += v[i];
  }
#pragma unroll
  for (int off = 1; off < 64; off <<= 1) s += __shfl_xor(s, off);
  if ((t & 63) == 0) red[t >> 6] = s;
  __syncthreads();
  s = red[0] + red[1] + red[2] + red[3];
  float mu = s * 0.0009765625f;
  float q = 0.f;
#pragma unroll
  for (int i = 0; i < 4; i++) { float d = v[i] - mu; q += d * d; }
  __syncthreads();
#pragma unroll
  for (int off = 1; off < 64; off <<= 1) q += __shfl_xor(q, off);
  if ((t & 63) == 0) red[t >> 6] = q;
  __syncthreads();
  q = red[0] + red[1] + red[2] + red[3];
  float rs = rsqrtf(q * 0.0009765625f + 1e-5f);
#pragma unroll
  for (int i = 0; i < 4; i++) {
    int c = t + 256 * i;
    float y = (v[i] - mu) * rs * g[c] + beta[c];
    if (outF) outF[(size_t)row * 1024 + c] = y;
    if (outB) outB[(size_t)row * 1024 + c] = f2bf(y);
  }
}

// ---------------------------------------------------------------------------
// Workspace (bytes), aliased by lifetime.
// ---------------------------------------------------------------------------
#define WS_BASEB   0            // [8192][1024] u16 = 16 MB (dead after QKV gemm)
#define WS_FUSB    16777216     // 16 MB (dead after QKV gemm)
#define WS_W       33554432     // 7 x [1024][1024] u16 = 14 MB
#define WS_QKV     48234496     // Q2 16MB | K2 16MB | Vt 16MB (dead after attn)
#define WS_ATTNO   98566144     // [8192][1024] u16 = 16 MB (dead after O gemm)
#define WS_X       115343360    // [8192][1024] f32 = 32 MB (ends 148897792)
#define WS_OB      WS_FUSB                  // [8192][1024] u16 (fusb dead)
#define WS_XB      WS_BASEB                 // [8192][1024] u16 (baseb dead)
#define WS_H1      WS_ATTNO                 // alias (attno dead)
#define WS_FFB     WS_QKV                   // alias Q2 (dead after attn)
#define WS_YB      (WS_QKV + 16777216)      // alias K2 (dead)

extern "C" void kernel_launch(void* const* d_in, const int* in_sizes, int n_in,
                              void* d_out, int out_size, void* d_ws, size_t ws_size,
                              hipStream_t stream) {
  const float* base   = (const float*)d_in[0];
  const float* fusion = (const float*)d_in[1];
  const float* Wq     = (const float*)d_in[2];
  const float* Wk     = (const float*)d_in[3];
  const float* Wv     = (const float*)d_in[4];
  const float* Wo     = (const float*)d_in[5];
  const float* g1     = (const float*)d_in[6];
  const float* b1     = (const float*)d_in[7];
  const float* g2     = (const float*)d_in[8];
  const float* b2     = (const float*)d_in[9];
  const float* fc1w   = (const float*)d_in[10];
  const float* fc1b   = (const float*)d_in[11];
  const float* fc2w   = (const float*)d_in[12];
  const float* fc2b   = (const float*)d_in[13];
  const float* rw     = (const float*)d_in[14];
  const float* rb     = (const float*)d_in[15];
  const float* alphap = (const float*)d_in[16];

  char* ws = (char*)d_ws;
  u16* baseb  = (u16*)(ws + WS_BASEB);
  u16* fusb   = (u16*)(ws + WS_FUSB);
  u16* wall   = (u16*)(ws + WS_W);        // wq|wk|wv|wo|fc1|fc2|rw
  u16* Q2     = (u16*)(ws + WS_QKV);      // K2 = Q2+8388608, Vt = Q2+16777216 (elems)
  u16* attno  = (u16*)(ws + WS_ATTNO);
  u16* obufb  = (u16*)(ws + WS_OB);
  float* x    = (float*)(ws + WS_X);
  u16* xb     = (u16*)(ws + WS_XB);
  u16* h1     = (u16*)(ws + WS_H1);
  u16* ffb    = (u16*)(ws + WS_FFB);
  u16* yb     = (u16*)(ws + WS_YB);

  float* final_out  = (float*)d_out;
  float* masked_out = final_out + 8388608;

  // 1. pack (vec4)
  pack_act<<<dim3(8192, 2), 256, 0, stream>>>(base, fusion, baseb, fusb);
  pack_w<<<dim3(1024, 7), 256, 0, stream>>>(Wq, Wk, Wv, Wo, fc1w, fc2w, rw, wall);

  dim3 gg(8, 64);

  // 2. QKV merged (z: 0=Q plain, 1=K swizzled, 2=Vt)
  gemm_bt<EPI_QKV><<<dim3(8, 64, 3), 256, 0, stream>>>(
      baseb, 1024, wall, 1024, 8192, 1024, 1024, nullptr, Q2, nullptr, fusb);

  // 3. attention (flat grid, XCD-swizzled inside)
  attn_kernel<<<dim3(1024), 256, 0, stream>>>(
      Q2, Q2 + 8388608, Q2 + 16777216, alphap, masked_out, attno);

  // 4. output proj (bf16 out) + LN1
  gemm_bt<EPI_BF16><<<gg, 256, 0, stream>>>(attno, 1024, wall + 3 * 1048576, 1024,
                                            8192, 1024, 1024, nullptr, obufb, nullptr, nullptr);
  ln_kernel<<<8192, 256, 0, stream>>>(base, obufb, g1, b1, x, xb);

  // 5. FFN + LN2
  gemm_bt<EPI_SILU_BF16><<<gg, 256, 0, stream>>>(xb, 1024, wall + 4 * 1048576, 1024,
                                                 8192, 1024, 1024, nullptr, h1, fc1b, nullptr);
  gemm_bt<EPI_SILU_BF16><<<gg, 256, 0, stream>>>(h1, 1024, wall + 5 * 1048576, 1024,
                                                 8192, 1024, 1024, nullptr, ffb, fc2b, nullptr);
  ln_kernel<<<8192, 256, 0, stream>>>(x, ffb, g2, b2, nullptr, yb);

  // 6. final projection
  gemm_bt<EPI_BIAS_F32><<<gg, 256, 0, stream>>>(yb, 1024, wall + 6 * 1048576, 1024,
                                                8192, 1024, 1024, final_out, nullptr, rb, nullptr);
}

// Round 3
// 977.180 us; speedup vs baseline: 1.0655x; 1.0140x over previous
//
#include <hip/hip_runtime.h>

// ============================================================================
// CrossAttention fused pipeline, MI355X gfx950.  Round 8.
// - R8 single lever: the four tail GEMMs (O-proj, fc1, fc2, final) move from
//   4-wave to 8-wave blocks (512 thr) at the SAME 128x128 tile and grid.
//   Grid 512 blocks = 2 blocks/CU was the hard occupancy cap: 8 waves/CU.
//   8-wave blocks double that to 16 waves/CU, hiding the per-k-step barrier
//   drain + LDS/MFMA latency.  Wave grid 2x4, each wave 64x32 out (acc 4x2).
//   QKV keeps the 4-wave kernel (1536 blocks = 5/CU = 20 waves/CU already).
// - R7 kept: XCD swizzles (GEMM chunked, attn bh-resident), attn setprio,
//   vec4 packs.  R6 kept: counted-vmcnt attn barrier.
// - GEMM: BK=32 m97-structure, XOR LDS swizzle, dbuf.
// - Attention: two-pass recompute, dbuf K/V staging, wave-local Ps handoff.
// ============================================================================

typedef unsigned short u16;
typedef __attribute__((ext_vector_type(8))) short  bf16x8;
typedef __attribute__((ext_vector_type(4))) short  s16x4;
typedef __attribute__((ext_vector_type(4))) float  f32x4;

#define GLL16(gp, lp) __builtin_amdgcn_global_load_lds(                     \
    (__attribute__((address_space(1))) const void*)(gp),                    \
    (__attribute__((address_space(3))) void*)(lp), 16, 0, 0)

__device__ __forceinline__ u16 f2bf(float x) {
  union { float f; unsigned u; } v; v.f = x;
  return (u16)((v.u + 0x7FFF + ((v.u >> 16) & 1)) >> 16);   // RNE
}
__device__ __forceinline__ float bf2f(u16 h) {
  union { unsigned u; float f; } v; v.u = ((unsigned)h) << 16;
  return v.f;
}
__device__ __forceinline__ f32x4 zero4() { f32x4 z = {0.f, 0.f, 0.f, 0.f}; return z; }

// ---------------------------------------------------------------------------
// Packing: activations (base,fusion) and 7 weights, fp32 -> bf16, x4 vector.
// ---------------------------------------------------------------------------
__global__ __launch_bounds__(256) void pack_act(const float* __restrict__ a,
                                                const float* __restrict__ b,
                                                u16* __restrict__ outa,
                                                u16* __restrict__ outb) {
  size_t i = (size_t)blockIdx.x * 256 + threadIdx.x;        // vec4 index
  const f32x4* in = (const f32x4*)(blockIdx.y ? b : a);
  s16x4* out = (s16x4*)(blockIdx.y ? outb : outa);
  f32x4 v = in[i];
  s16x4 o;
  o[0] = (short)f2bf(v[0]); o[1] = (short)f2bf(v[1]);
  o[2] = (short)f2bf(v[2]); o[3] = (short)f2bf(v[3]);
  out[i] = o;
}

__global__ __launch_bounds__(256) void pack_w(
    const float* __restrict__ w0, const float* __restrict__ w1,
    const float* __restrict__ w2, const float* __restrict__ w3,
    const float* __restrict__ w4, const float* __restrict__ w5,
    const float* __restrict__ w6, u16* __restrict__ out) {
  size_t i = (size_t)blockIdx.x * 256 + threadIdx.x;        // vec4 index
  const float* in;
  switch (blockIdx.y) {
    case 0: in = w0; break;  case 1: in = w1; break;
    case 2: in = w2; break;  case 3: in = w3; break;
    case 4: in = w4; break;  case 5: in = w5; break;
    default: in = w6; break;
  }
  f32x4 v = ((const f32x4*)in)[i];
  s16x4 o;
  o[0] = (short)f2bf(v[0]); o[1] = (short)f2bf(v[1]);
  o[2] = (short)f2bf(v[2]); o[3] = (short)f2bf(v[3]);
  ((s16x4*)(out + (size_t)blockIdx.y * 1048576))[i] = o;
}

// ---------------------------------------------------------------------------
// GEMM (4-wave, QKV only): C[M,N] = A[M,K] @ W[N,K]^T, bf16, BK=32, dbuf LDS.
// LDS row r holds 4x16B blocks; global block g stored at slot g ^ ((r>>1)&3).
// ---------------------------------------------------------------------------
#define EPI_QKV       0  // z=0: Q2 plain; z=1: K2 swizzled; z=2: Vt swizzled-T
#define EPI_BF16      1  // plain bf16 row-major
#define EPI_SILU_BF16 4  // silu(v+bias) -> bf16
#define EPI_BIAS_F32  6  // v+bias -> f32

template <int EPI>
__global__ __launch_bounds__(256) void gemm_bt(
    const u16* __restrict__ A, int lda,
    const u16* __restrict__ W, int ldw,
    int M, int N, int K,
    float* __restrict__ outF, u16* __restrict__ outU,
    const float* __restrict__ bias,
    const u16* __restrict__ A2) {
  __shared__ u16 As[2][128 * 32];   // 2 x 8 KB
  __shared__ u16 Bs[2][128 * 32];   // 2 x 8 KB
  int tid = threadIdx.x;
  int l = tid & 63, w = tid >> 6;
  int wr = w >> 1, wc = w & 1, lr = l & 15, lq = l >> 4;

  // XCD-chunked swizzle: each XCD gets 64 consecutive logical blocks =
  // 8 m-panels (2MB A) + all n (2MB W) = its 4MB L2.  512 % 8 == 0.
  int fid = blockIdx.y * 8 + blockIdx.x;
  int swz = (fid & 7) * 64 + (fid >> 3);
  int m0 = (swz >> 3) * 128, n0 = (swz & 7) * 128;

  const u16* Ap = A;
  const u16* Wp = W;
  u16* outUp = outU;
  if constexpr (EPI == EPI_QKV) {
    int z = blockIdx.z;
    if (z) Ap = A2;                      // K,V read fusion
    Wp = W + (size_t)z * 1048576;        // wq / wk / wv
    outUp = outU + (size_t)z * 8388608;  // Q2 / K2 / Vt
  }

  f32x4 acc[4][4];
#pragma unroll
  for (int i = 0; i < 4; i++)
#pragma unroll
    for (int j = 0; j < 4; j++) acc[i][j] = zero4();

  auto stage = [&](const u16* src, int ld, int r0, int k0, u16* lds) {
#pragma unroll
    for (int j = 0; j < 2; ++j) {
      int seg = j * 256 + tid;               // 512 segs x 16B
      int row = seg >> 2, sp = seg & 3;
      const u16* g = src + (size_t)(r0 + row) * ld + k0 +
                     ((sp ^ ((row >> 1) & 3)) << 3);
      GLL16(g, lds + seg * 8);               // lane-contiguous LDS dest
    }
  };

  int nk = K >> 5;
  stage(Ap, lda, m0, 0, As[0]);
  stage(Wp, ldw, n0, 0, Bs[0]);
  for (int kt = 0; kt < nk; ++kt) {
    __syncthreads();                          // drains stage(kt); prev reads done
    if (kt + 1 < nk) {
      stage(Ap, lda, m0, (kt + 1) << 5, As[(kt + 1) & 1]);
      stage(Wp, ldw, n0, (kt + 1) << 5, Bs[(kt + 1) & 1]);
    }
    const u16* Ab = As[kt & 1];
    const u16* Bb = Bs[kt & 1];
    bf16x8 af[4], bw[4];
    int slot = (lq ^ ((lr >> 1) & 3)) << 3;
#pragma unroll
    for (int mi = 0; mi < 4; mi++)
      af[mi] = *(const bf16x8*)&Ab[(wr * 64 + mi * 16 + lr) * 32 + slot];
#pragma unroll
    for (int ni = 0; ni < 4; ni++)
      bw[ni] = *(const bf16x8*)&Bb[(wc * 64 + ni * 16 + lr) * 32 + slot];
#pragma unroll
    for (int mi = 0; mi < 4; mi++)
#pragma unroll
      for (int ni = 0; ni < 4; ni++)
        acc[mi][ni] = __builtin_amdgcn_mfma_f32_16x16x32_bf16(af[mi], bw[ni],
                                                              acc[mi][ni], 0, 0, 0);
  }

#pragma unroll
  for (int mi = 0; mi < 4; mi++) {
#pragma unroll
    for (int ni = 0; ni < 4; ni++) {
      int col = n0 + wc * 64 + ni * 16 + lr;
#pragma unroll
      for (int r = 0; r < 4; r++) {
        int row = m0 + wr * 64 + mi * 16 + lq * 4 + r;
        float v = acc[mi][ni][r];
        if constexpr (EPI == EPI_QKV) {
          int b = row >> 10, t = row & 1023, h = col >> 6, d = col & 63;
          int z = blockIdx.z;
          if (z == 0) {                       // Q2: [bh][t][64] plain
            outUp[((size_t)(b * 16 + h) * 1024 + t) * 64 + d] = f2bf(v);
          } else if (z == 1) {                // K2: XOR-(t&7) swizzled rows
            size_t base = ((size_t)(b * 16 + h) * 1024 + t) * 64;
            outUp[base + (((d >> 3) ^ (t & 7)) << 3) + (d & 7)] = f2bf(v);
          } else {                            // Vt: [bh][d][t], XOR-(d&7) per 64-chunk
            size_t o = ((size_t)(b * 16 + h) * 64 + d) * 1024 + (t & ~63) +
                       ((((t >> 3) & 7) ^ (d & 7)) << 3) + (t & 7);
            outUp[o] = f2bf(v);
          }
        } else if constexpr (EPI == EPI_BF16) {
          outUp[(size_t)row * N + col] = f2bf(v);
        } else if constexpr (EPI == EPI_SILU_BF16) {
          float z = v + bias[col];
          outUp[(size_t)row * N + col] = f2bf(z / (1.f + __expf(-z)));
        } else {  // EPI_BIAS_F32
          outF[(size_t)row * N + col] = v + bias[col];
        }
      }
    }
  }
}

// ---------------------------------------------------------------------------
// GEMM 8-wave (tail GEMMs): same 128x128 tile / grid / LDS, 512 threads.
// Wave grid 2x4, each wave 64x32 out (acc 4x2).  2 blocks/CU -> 16 waves/CU.
// ---------------------------------------------------------------------------
template <int EPI>
__global__ __launch_bounds__(512) void gemm_bt8(
    const u16* __restrict__ A, int lda,
    const u16* __restrict__ W, int ldw,
    int M, int N, int K,
    float* __restrict__ outF, u16* __restrict__ outU,
    const float* __restrict__ bias) {
  __shared__ u16 As[2][128 * 32];   // 2 x 8 KB
  __shared__ u16 Bs[2][128 * 32];   // 2 x 8 KB
  int tid = threadIdx.x;
  int l = tid & 63, w = tid >> 6;                  // 8 waves
  int wr = w >> 2, wc = w & 3, lr = l & 15, lq = l >> 4;

  int fid = blockIdx.y * 8 + blockIdx.x;
  int swz = (fid & 7) * 64 + (fid >> 3);
  int m0 = (swz >> 3) * 128, n0 = (swz & 7) * 128;

  f32x4 acc[4][2];
#pragma unroll
  for (int i = 0; i < 4; i++)
#pragma unroll
    for (int j = 0; j < 2; j++) acc[i][j] = zero4();

  auto stage = [&](const u16* src, int ld, int r0, int k0, u16* lds) {
    int seg = tid;                           // 512 segs x 16B, one per thread
    int row = seg >> 2, sp = seg & 3;
    const u16* g = src + (size_t)(r0 + row) * ld + k0 +
                   ((sp ^ ((row >> 1) & 3)) << 3);
    GLL16(g, lds + seg * 8);
  };

  int nk = K >> 5;
  stage(A, lda, m0, 0, As[0]);
  stage(W, ldw, n0, 0, Bs[0]);
  for (int kt = 0; kt < nk; ++kt) {
    __syncthreads();
    if (kt + 1 < nk) {
      stage(A, lda, m0, (kt + 1) << 5, As[(kt + 1) & 1]);
      stage(W, ldw, n0, (kt + 1) << 5, Bs[(kt + 1) & 1]);
    }
    const u16* Ab = As[kt & 1];
    const u16* Bb = Bs[kt & 1];
    bf16x8 af[4], bw[2];
    int slot = (lq ^ ((lr >> 1) & 3)) << 3;
#pragma unroll
    for (int mi = 0; mi < 4; mi++)
      af[mi] = *(const bf16x8*)&Ab[(wr * 64 + mi * 16 + lr) * 32 + slot];
#pragma unroll
    for (int ni = 0; ni < 2; ni++)
      bw[ni] = *(const bf16x8*)&Bb[(wc * 32 + ni * 16 + lr) * 32 + slot];
#pragma unroll
    for (int mi = 0; mi < 4; mi++)
#pragma unroll
      for (int ni = 0; ni < 2; ni++)
        acc[mi][ni] = __builtin_amdgcn_mfma_f32_16x16x32_bf16(af[mi], bw[ni],
                                                              acc[mi][ni], 0, 0, 0);
  }

#pragma unroll
  for (int mi = 0; mi < 4; mi++) {
#pragma unroll
    for (int ni = 0; ni < 2; ni++) {
      int col = n0 + wc * 32 + ni * 16 + lr;
#pragma unroll
      for (int r = 0; r < 4; r++) {
        int row = m0 + wr * 64 + mi * 16 + lq * 4 + r;
        float v = acc[mi][ni][r];
        if constexpr (EPI == EPI_BF16) {
          outU[(size_t)row * N + col] = f2bf(v);
        } else if constexpr (EPI == EPI_SILU_BF16) {
          float z = v + bias[col];
          outU[(size_t)row * N + col] = f2bf(z / (1.f + __expf(-z)));
        } else {  // EPI_BIAS_F32
          outF[(size_t)row * N + col] = v + bias[col];
        }
      }
    }
  }
}

// ---------------------------------------------------------------------------
// Attention: two-pass recompute, plain bf16, dbuf K/V staging.
// Block 256 thr (4 waves), 128 q-rows (32/wave).  Grid (1024).
// XCD swizzle: qi = bid>>7, bh = (bid&7)*16 + ((bid>>3)&15).
// Q2 [bh][t][64] plain; K2 [bh][t][64] XOR-(t&7); Vt [bh][d][1024] XOR-(d&7).
// ---------------------------------------------------------------------------
__global__ __launch_bounds__(256) void attn_kernel(
    const u16* __restrict__ Q2, const u16* __restrict__ K2,
    const u16* __restrict__ Vt, const float* __restrict__ alphap,
    float* __restrict__ masked_out, u16* __restrict__ attn_out) {
  __shared__ __align__(16) u16 Ks[2][4096];        // 16 KB
  __shared__ __align__(16) u16 Vs[2][4096];        // 16 KB
  __shared__ __align__(16) u16 Ps[4][2][16 * 72];  // 18 KB

  int tid = threadIdx.x;
  int l = tid & 63, w = tid >> 6, lr = l & 15, lq = l >> 4;

  int bid = blockIdx.x;
  int qi  = bid >> 7;                              // 0..7 q-chunk
  int bh  = (bid & 7) * 16 + ((bid >> 3) & 15);    // 0..127, XCD-resident
  int h = bh & 15, b = bh >> 4;
  int q0 = qi * 128;

  const u16* Qb = Q2 + (size_t)bh * 1024 * 64;
  const u16* Kb = K2 + (size_t)bh * 1024 * 64;
  const u16* Vb = Vt + (size_t)bh * 64 * 1024;
  float alpha = alphap[0];
  int qw = q0 + w * 32;

  auto stageK = [&](int kc, u16* dst) {
#pragma unroll
    for (int j = 0; j < 2; ++j) {
      int seg = j * 256 + tid;
      GLL16(Kb + (size_t)kc * 4096 + seg * 8, dst + seg * 8);
    }
  };
  auto stageV = [&](int kc, u16* dst) {
#pragma unroll
    for (int j = 0; j < 2; ++j) {
      int seg = j * 256 + tid;                  // row d = seg>>3, part = seg&7
      GLL16(Vb + (size_t)(seg >> 3) * 1024 + kc * 64 + (seg & 7) * 8, dst + seg * 8);
    }
  };

  // Q fragments in registers: [sub 16-rows][k-chunk]
  bf16x8 qf[2][2];
#pragma unroll
  for (int s = 0; s < 2; s++)
#pragma unroll
    for (int kt = 0; kt < 2; kt++)
      qf[s][kt] = *(const bf16x8*)(Qb + (size_t)(qw + s * 16 + lr) * 64 + kt * 32 + lq * 8);

  float s1[2][4] = {{0.f, 0.f, 0.f, 0.f}, {0.f, 0.f, 0.f, 0.f}};

  // ---- pass 1 ----
  stageK(0, Ks[0]);
  for (int kc = 0; kc < 16; ++kc) {
    __syncthreads();                            // drains stage(kc); prev reads done
    if (kc + 1 < 16) stageK(kc + 1, Ks[(kc + 1) & 1]);
    const u16* Kc = Ks[kc & 1];
    f32x4 acc[2][4];
#pragma unroll
    for (int s = 0; s < 2; s++)
#pragma unroll
      for (int ni = 0; ni < 4; ni++) acc[s][ni] = zero4();
    __builtin_amdgcn_s_setprio(1);              // T5: favor MFMA wave (m191)
#pragma unroll
    for (int ni = 0; ni < 4; ++ni) {
      int t = ni * 16 + lr;
      bf16x8 k0 = *(const bf16x8*)&Kc[t * 64 + (((0 + lq) ^ (lr & 7)) << 3)];
      bf16x8 k1 = *(const bf16x8*)&Kc[t * 64 + (((4 + lq) ^ (lr & 7)) << 3)];
#pragma unroll
      for (int s = 0; s < 2; s++) {
        acc[s][ni] = __builtin_amdgcn_mfma_f32_16x16x32_bf16(qf[s][0], k0, acc[s][ni], 0, 0, 0);
        acc[s][ni] = __builtin_amdgcn_mfma_f32_16x16x32_bf16(qf[s][1], k1, acc[s][ni], 0, 0, 0);
      }
    }
    __builtin_amdgcn_s_setprio(0);
#pragma unroll
    for (int s = 0; s < 2; s++)
#pragma unroll
      for (int ni = 0; ni < 4; ni++)
#pragma unroll
        for (int r = 0; r < 4; r++)
          s1[s][r] += __expf(acc[s][ni][r] * 0.125f);
  }
#pragma unroll
  for (int s = 0; s < 2; s++)
#pragma unroll
    for (int r = 0; r < 4; r++) {
      float v = s1[s][r];
      v += __shfl_xor(v, 1); v += __shfl_xor(v, 2);
      v += __shfl_xor(v, 4); v += __shfl_xor(v, 8);
      s1[s][r] = 1.0f / v;
    }

  // ---- pass 2 ----
  float s2[2][4] = {{0.f, 0.f, 0.f, 0.f}, {0.f, 0.f, 0.f, 0.f}};
  f32x4 oacc[2][4];
#pragma unroll
  for (int s = 0; s < 2; s++)
#pragma unroll
    for (int dg = 0; dg < 4; dg++) oacc[s][dg] = zero4();

  stageK(0, Ks[0]);                             // Ks[0] reads drained at kc=15 sync
  stageV(0, Vs[0]);
  for (int kc = 0; kc < 16; ++kc) {
    // counted-vmcnt barrier (R6): staging loads complete, masked stores
    // drain lazily under next iteration's compute.
    if (kc == 0) {
      asm volatile("s_waitcnt vmcnt(0) lgkmcnt(0)" ::: "memory");
    } else {
      asm volatile("s_waitcnt vmcnt(32) lgkmcnt(0)" ::: "memory");
    }
    __builtin_amdgcn_s_barrier();
    __builtin_amdgcn_sched_barrier(0);
    if (kc + 1 < 16) {
      stageK(kc + 1, Ks[(kc + 1) & 1]);
      stageV(kc + 1, Vs[(kc + 1) & 1]);
    }
    const u16* Kc = Ks[kc & 1];
    const u16* Vc = Vs[kc & 1];

    f32x4 acc[2][4];
#pragma unroll
    for (int s = 0; s < 2; s++)
#pragma unroll
      for (int ni = 0; ni < 4; ni++) acc[s][ni] = zero4();
    __builtin_amdgcn_s_setprio(1);              // T5
#pragma unroll
    for (int ni = 0; ni < 4; ++ni) {
      int t = ni * 16 + lr;
      bf16x8 k0 = *(const bf16x8*)&Kc[t * 64 + (((0 + lq) ^ (lr & 7)) << 3)];
      bf16x8 k1 = *(const bf16x8*)&Kc[t * 64 + (((4 + lq) ^ (lr & 7)) << 3)];
#pragma unroll
      for (int s = 0; s < 2; s++) {
        acc[s][ni] = __builtin_amdgcn_mfma_f32_16x16x32_bf16(qf[s][0], k0, acc[s][ni], 0, 0, 0);
        acc[s][ni] = __builtin_amdgcn_mfma_f32_16x16x32_bf16(qf[s][1], k1, acc[s][ni], 0, 0, 0);
      }
    }
    __builtin_amdgcn_s_setprio(0);

#pragma unroll
    for (int s = 0; s < 2; s++) {
#pragma unroll
      for (int ni = 0; ni < 4; ni++) {
#pragma unroll
        for (int r = 0; r < 4; r++) {
          float e = __expf(acc[s][ni][r] * 0.125f);
          float a = e * s1[s][r];
          a = (a >= alpha) ? a : 0.0f;
          size_t row = (size_t)bh * 1024 + qw + s * 16 + lq * 4 + r;
          masked_out[row * 1024 + kc * 64 + ni * 16 + lr] = a;
          float p = __expf(a);
          s2[s][r] += p;
          Ps[w][s][(lq * 4 + r) * 72 + ni * 16 + lr] = f2bf(p);
        }
      }
    }
    // wave-local Ps handoff: Ps[w] is written and read only by wave w.
    asm volatile("s_waitcnt lgkmcnt(0)" ::: "memory");

    bf16x8 pf[2][2];
#pragma unroll
    for (int s = 0; s < 2; s++)
#pragma unroll
      for (int kt = 0; kt < 2; kt++)
        pf[s][kt] = *(const bf16x8*)&Ps[w][s][lr * 72 + kt * 32 + lq * 8];
    __builtin_amdgcn_s_setprio(1);              // T5
#pragma unroll
    for (int dg = 0; dg < 4; dg++) {
      int d = dg * 16 + lr;
      bf16x8 v0 = *(const bf16x8*)&Vc[d * 64 + (((0 + lq) ^ (lr & 7)) << 3)];
      bf16x8 v1 = *(const bf16x8*)&Vc[d * 64 + (((4 + lq) ^ (lr & 7)) << 3)];
#pragma unroll
      for (int s = 0; s < 2; s++) {
        oacc[s][dg] = __builtin_amdgcn_mfma_f32_16x16x32_bf16(pf[s][0], v0, oacc[s][dg], 0, 0, 0);
        oacc[s][dg] = __builtin_amdgcn_mfma_f32_16x16x32_bf16(pf[s][1], v1, oacc[s][dg], 0, 0, 0);
      }
    }
    __builtin_amdgcn_s_setprio(0);
  }

#pragma unroll
  for (int s = 0; s < 2; s++)
#pragma unroll
    for (int r = 0; r < 4; r++) {
      float v = s2[s][r];
      v += __shfl_xor(v, 1); v += __shfl_xor(v, 2);
      v += __shfl_xor(v, 4); v += __shfl_xor(v, 8);
      s2[s][r] = 1.0f / v;
    }
#pragma unroll
  for (int s = 0; s < 2; s++)
#pragma unroll
    for (int dg = 0; dg < 4; dg++)
#pragma unroll
      for (int r = 0; r < 4; r++) {
        int q = qw + s * 16 + lq * 4 + r;
        attn_out[(size_t)(b * 1024 + q) * 1024 + h * 64 + dg * 16 + lr] =
            f2bf(oacc[s][dg][r] * s2[s][r]);
      }
}

// ---------------------------------------------------------------------------
// LayerNorm over D=1024: y = (A + bf2f(Bv) - mu)*rsqrt(var+eps)*g + beta
// ---------------------------------------------------------------------------
__global__ __launch_bounds__(256) void ln_kernel(
    const float* __restrict__ A, const u16* __restrict__ Bv,
    const float* __restrict__ g, const float* __restrict__ beta,
    float* __restrict__ outF, u16* __restrict__ outB) {
  __shared__ float red[4];
  int row = blockIdx.x, t = threadIdx.x;
  const float* pa = A + (size_t)row * 1024;
  const u16* pb = Bv + (size_t)row * 1024;
  float v[4];
  float s = 0.f;
#pragma unroll
  for (int i = 0; i < 4; i++) {
    int c = t + 256 * i;
    v[i] = pa[c] + bf2f(pb[c]);
    s += v[i];
  }
#pragma unroll
  for (int off = 1; off < 64; off <<= 1) s += __shfl_xor(s, off);
  if ((t & 63) == 0) red[t >> 6] = s;
  __syncthreads();
  s = red[0] + red[1] + red[2] + red[3];
  float mu = s * 0.0009765625f;
  float q = 0.f;
#pragma unroll
  for (int i = 0; i < 4; i++) { float d = v[i] - mu; q += d * d; }
  __syncthreads();
#pragma unroll
  for (int off = 1; off < 64; off <<= 1) q += __shfl_xor(q, off);
  if ((t & 63) == 0) red[t >> 6] = q;
  __syncthreads();
  q = red[0] + red[1] + red[2] + red[3];
  float rs = rsqrtf(q * 0.0009765625f + 1e-5f);
#pragma unroll
  for (int i = 0; i < 4; i++) {
    int c = t + 256 * i;
    float y = (v[i] - mu) * rs * g[c] + beta[c];
    if (outF) outF[(size_t)row * 1024 + c] = y;
    if (outB) outB[(size_t)row * 1024 + c] = f2bf(y);
  }
}

// ---------------------------------------------------------------------------
// Workspace (bytes), aliased by lifetime.
// ---------------------------------------------------------------------------
#define WS_BASEB   0            // [8192][1024] u16 = 16 MB (dead after QKV gemm)
#define WS_FUSB    16777216     // 16 MB (dead after QKV gemm)
#define WS_W       33554432     // 7 x [1024][1024] u16 = 14 MB
#define WS_QKV     48234496     // Q2 16MB | K2 16MB | Vt 16MB (dead after attn)
#define WS_ATTNO   98566144     // [8192][1024] u16 = 16 MB (dead after O gemm)
#define WS_X       115343360    // [8192][1024] f32 = 32 MB (ends 148897792)
#define WS_OB      WS_FUSB                  // [8192][1024] u16 (fusb dead)
#define WS_XB      WS_BASEB                 // [8192][1024] u16 (baseb dead)
#define WS_H1      WS_ATTNO                 // alias (attno dead)
#define WS_FFB     WS_QKV                   // alias Q2 (dead after attn)
#define WS_YB      (WS_QKV + 16777216)      // alias K2 (dead)

extern "C" void kernel_launch(void* const* d_in, const int* in_sizes, int n_in,
                              void* d_out, int out_size, void* d_ws, size_t ws_size,
                              hipStream_t stream) {
  const float* base   = (const float*)d_in[0];
  const float* fusion = (const float*)d_in[1];
  const float* Wq     = (const float*)d_in[2];
  const float* Wk     = (const float*)d_in[3];
  const float* Wv     = (const float*)d_in[4];
  const float* Wo     = (const float*)d_in[5];
  const float* g1     = (const float*)d_in[6];
  const float* b1     = (const float*)d_in[7];
  const float* g2     = (const float*)d_in[8];
  const float* b2     = (const float*)d_in[9];
  const float* fc1w   = (const float*)d_in[10];
  const float* fc1b   = (const float*)d_in[11];
  const float* fc2w   = (const float*)d_in[12];
  const float* fc2b   = (const float*)d_in[13];
  const float* rw     = (const float*)d_in[14];
  const float* rb     = (const float*)d_in[15];
  const float* alphap = (const float*)d_in[16];

  char* ws = (char*)d_ws;
  u16* baseb  = (u16*)(ws + WS_BASEB);
  u16* fusb   = (u16*)(ws + WS_FUSB);
  u16* wall   = (u16*)(ws + WS_W);        // wq|wk|wv|wo|fc1|fc2|rw
  u16* Q2     = (u16*)(ws + WS_QKV);      // K2 = Q2+8388608, Vt = Q2+16777216 (elems)
  u16* attno  = (u16*)(ws + WS_ATTNO);
  u16* obufb  = (u16*)(ws + WS_OB);
  float* x    = (float*)(ws + WS_X);
  u16* xb     = (u16*)(ws + WS_XB);
  u16* h1     = (u16*)(ws + WS_H1);
  u16* ffb    = (u16*)(ws + WS_FFB);
  u16* yb     = (u16*)(ws + WS_YB);

  float* final_out  = (float*)d_out;
  float* masked_out = final_out + 8388608;

  // 1. pack (vec4)
  pack_act<<<dim3(8192, 2), 256, 0, stream>>>(base, fusion, baseb, fusb);
  pack_w<<<dim3(1024, 7), 256, 0, stream>>>(Wq, Wk, Wv, Wo, fc1w, fc2w, rw, wall);

  dim3 gg(8, 64);

  // 2. QKV merged (z: 0=Q plain, 1=K swizzled, 2=Vt) - 4-wave kernel
  gemm_bt<EPI_QKV><<<dim3(8, 64, 3), 256, 0, stream>>>(
      baseb, 1024, wall, 1024, 8192, 1024, 1024, nullptr, Q2, nullptr, fusb);

  // 3. attention (flat grid, XCD-swizzled inside)
  attn_kernel<<<dim3(1024), 256, 0, stream>>>(
      Q2, Q2 + 8388608, Q2 + 16777216, alphap, masked_out, attno);

  // 4. output proj (bf16 out, 8-wave) + LN1
  gemm_bt8<EPI_BF16><<<gg, 512, 0, stream>>>(attno, 1024, wall + 3 * 1048576, 1024,
                                             8192, 1024, 1024, nullptr, obufb, nullptr);
  ln_kernel<<<8192, 256, 0, stream>>>(base, obufb, g1, b1, x, xb);

  // 5. FFN + LN2 (8-wave)
  gemm_bt8<EPI_SILU_BF16><<<gg, 512, 0, stream>>>(xb, 1024, wall + 4 * 1048576, 1024,
                                                  8192, 1024, 1024, nullptr, h1, fc1b);
  gemm_bt8<EPI_SILU_BF16><<<gg, 512, 0, stream>>>(h1, 1024, wall + 5 * 1048576, 1024,
                                                  8192, 1024, 1024, nullptr, ffb, fc2b);
  ln_kernel<<<8192, 256, 0, stream>>>(x, ffb, g2, b2, nullptr, yb);

  // 6. final projection (8-wave)
  gemm_bt8<EPI_BIAS_F32><<<gg, 512, 0, stream>>>(yb, 1024, wall + 6 * 1048576, 1024,
                                                 8192, 1024, 1024, final_out, nullptr, rb);
}

// Round 4
// 939.763 us; speedup vs baseline: 1.1080x; 1.0398x over previous
//
#include <hip/hip_runtime.h>

// ============================================================================
// CrossAttention fused pipeline, MI355X gfx950.  Round 9.
// - R9 lever 1: tail GEMMs BK=32 -> BK=64.  Grid-capped at 2 blocks/CU, so
//   64KB LDS costs nothing; barrier+vmcnt(0)-drain pairs halve (32 -> 16),
//   each amortized over 2x MFMA+ds_read work (m233: the 2-phase drain is
//   ~72% overhead and wave-count-invariant -- R8's occupancy null proved it).
// - R9 lever 2: attention 8 waves x 16 q-rows (512 thr, same 128 rows and
//   grid).  Halves each wave's serial MFMA->exp->store->Ps chain per kc,
//   drops VGPR pressure, LDS stays 50KB -> up to 3 blocks/CU (>=16 waves).
//   vmcnt barrier: 2 staging loads + 16 stores/kc -> s_waitcnt vmcnt(16).
// - Kept: XCD swizzles (R7), attn setprio (R7), vec4 packs (R7), QKV 4-wave
//   BK=32 GEMM (20 waves/CU, healthy).
// ============================================================================

typedef unsigned short u16;
typedef __attribute__((ext_vector_type(8))) short  bf16x8;
typedef __attribute__((ext_vector_type(4))) short  s16x4;
typedef __attribute__((ext_vector_type(4))) float  f32x4;

#define GLL16(gp, lp) __builtin_amdgcn_global_load_lds(                     \
    (__attribute__((address_space(1))) const void*)(gp),                    \
    (__attribute__((address_space(3))) void*)(lp), 16, 0, 0)

__device__ __forceinline__ u16 f2bf(float x) {
  union { float f; unsigned u; } v; v.f = x;
  return (u16)((v.u + 0x7FFF + ((v.u >> 16) & 1)) >> 16);   // RNE
}
__device__ __forceinline__ float bf2f(u16 h) {
  union { unsigned u; float f; } v; v.u = ((unsigned)h) << 16;
  return v.f;
}
__device__ __forceinline__ f32x4 zero4() { f32x4 z = {0.f, 0.f, 0.f, 0.f}; return z; }

// ---------------------------------------------------------------------------
// Packing: activations (base,fusion) and 7 weights, fp32 -> bf16, x4 vector.
// ---------------------------------------------------------------------------
__global__ __launch_bounds__(256) void pack_act(const float* __restrict__ a,
                                                const float* __restrict__ b,
                                                u16* __restrict__ outa,
                                                u16* __restrict__ outb) {
  size_t i = (size_t)blockIdx.x * 256 + threadIdx.x;        // vec4 index
  const f32x4* in = (const f32x4*)(blockIdx.y ? b : a);
  s16x4* out = (s16x4*)(blockIdx.y ? outb : outa);
  f32x4 v = in[i];
  s16x4 o;
  o[0] = (short)f2bf(v[0]); o[1] = (short)f2bf(v[1]);
  o[2] = (short)f2bf(v[2]); o[3] = (short)f2bf(v[3]);
  out[i] = o;
}

__global__ __launch_bounds__(256) void pack_w(
    const float* __restrict__ w0, const float* __restrict__ w1,
    const float* __restrict__ w2, const float* __restrict__ w3,
    const float* __restrict__ w4, const float* __restrict__ w5,
    const float* __restrict__ w6, u16* __restrict__ out) {
  size_t i = (size_t)blockIdx.x * 256 + threadIdx.x;        // vec4 index
  const float* in;
  switch (blockIdx.y) {
    case 0: in = w0; break;  case 1: in = w1; break;
    case 2: in = w2; break;  case 3: in = w3; break;
    case 4: in = w4; break;  case 5: in = w5; break;
    default: in = w6; break;
  }
  f32x4 v = ((const f32x4*)in)[i];
  s16x4 o;
  o[0] = (short)f2bf(v[0]); o[1] = (short)f2bf(v[1]);
  o[2] = (short)f2bf(v[2]); o[3] = (short)f2bf(v[3]);
  ((s16x4*)(out + (size_t)blockIdx.y * 1048576))[i] = o;
}

// ---------------------------------------------------------------------------
// GEMM (4-wave, QKV only): C[M,N] = A[M,K] @ W[N,K]^T, bf16, BK=32, dbuf LDS.
// LDS row r holds 4x16B blocks; global block g stored at slot g ^ ((r>>1)&3).
// ---------------------------------------------------------------------------
#define EPI_QKV       0  // z=0: Q2 plain; z=1: K2 swizzled; z=2: Vt swizzled-T
#define EPI_BF16      1  // plain bf16 row-major
#define EPI_SILU_BF16 4  // silu(v+bias) -> bf16
#define EPI_BIAS_F32  6  // v+bias -> f32

template <int EPI>
__global__ __launch_bounds__(256) void gemm_bt(
    const u16* __restrict__ A, int lda,
    const u16* __restrict__ W, int ldw,
    int M, int N, int K,
    float* __restrict__ outF, u16* __restrict__ outU,
    const float* __restrict__ bias,
    const u16* __restrict__ A2) {
  __shared__ u16 As[2][128 * 32];   // 2 x 8 KB
  __shared__ u16 Bs[2][128 * 32];   // 2 x 8 KB
  int tid = threadIdx.x;
  int l = tid & 63, w = tid >> 6;
  int wr = w >> 1, wc = w & 1, lr = l & 15, lq = l >> 4;

  // XCD-chunked swizzle: each XCD gets 64 consecutive logical blocks.
  int fid = blockIdx.y * 8 + blockIdx.x;
  int swz = (fid & 7) * 64 + (fid >> 3);
  int m0 = (swz >> 3) * 128, n0 = (swz & 7) * 128;

  const u16* Ap = A;
  const u16* Wp = W;
  u16* outUp = outU;
  if constexpr (EPI == EPI_QKV) {
    int z = blockIdx.z;
    if (z) Ap = A2;                      // K,V read fusion
    Wp = W + (size_t)z * 1048576;        // wq / wk / wv
    outUp = outU + (size_t)z * 8388608;  // Q2 / K2 / Vt
  }

  f32x4 acc[4][4];
#pragma unroll
  for (int i = 0; i < 4; i++)
#pragma unroll
    for (int j = 0; j < 4; j++) acc[i][j] = zero4();

  auto stage = [&](const u16* src, int ld, int r0, int k0, u16* lds) {
#pragma unroll
    for (int j = 0; j < 2; ++j) {
      int seg = j * 256 + tid;               // 512 segs x 16B
      int row = seg >> 2, sp = seg & 3;
      const u16* g = src + (size_t)(r0 + row) * ld + k0 +
                     ((sp ^ ((row >> 1) & 3)) << 3);
      GLL16(g, lds + seg * 8);               // lane-contiguous LDS dest
    }
  };

  int nk = K >> 5;
  stage(Ap, lda, m0, 0, As[0]);
  stage(Wp, ldw, n0, 0, Bs[0]);
  for (int kt = 0; kt < nk; ++kt) {
    __syncthreads();                          // drains stage(kt); prev reads done
    if (kt + 1 < nk) {
      stage(Ap, lda, m0, (kt + 1) << 5, As[(kt + 1) & 1]);
      stage(Wp, ldw, n0, (kt + 1) << 5, Bs[(kt + 1) & 1]);
    }
    const u16* Ab = As[kt & 1];
    const u16* Bb = Bs[kt & 1];
    bf16x8 af[4], bw[4];
    int slot = (lq ^ ((lr >> 1) & 3)) << 3;
#pragma unroll
    for (int mi = 0; mi < 4; mi++)
      af[mi] = *(const bf16x8*)&Ab[(wr * 64 + mi * 16 + lr) * 32 + slot];
#pragma unroll
    for (int ni = 0; ni < 4; ni++)
      bw[ni] = *(const bf16x8*)&Bb[(wc * 64 + ni * 16 + lr) * 32 + slot];
#pragma unroll
    for (int mi = 0; mi < 4; mi++)
#pragma unroll
      for (int ni = 0; ni < 4; ni++)
        acc[mi][ni] = __builtin_amdgcn_mfma_f32_16x16x32_bf16(af[mi], bw[ni],
                                                              acc[mi][ni], 0, 0, 0);
  }

#pragma unroll
  for (int mi = 0; mi < 4; mi++) {
#pragma unroll
    for (int ni = 0; ni < 4; ni++) {
      int col = n0 + wc * 64 + ni * 16 + lr;
#pragma unroll
      for (int r = 0; r < 4; r++) {
        int row = m0 + wr * 64 + mi * 16 + lq * 4 + r;
        float v = acc[mi][ni][r];
        if constexpr (EPI == EPI_QKV) {
          int b = row >> 10, t = row & 1023, h = col >> 6, d = col & 63;
          int z = blockIdx.z;
          if (z == 0) {                       // Q2: [bh][t][64] plain
            outUp[((size_t)(b * 16 + h) * 1024 + t) * 64 + d] = f2bf(v);
          } else if (z == 1) {                // K2: XOR-(t&7) swizzled rows
            size_t base = ((size_t)(b * 16 + h) * 1024 + t) * 64;
            outUp[base + (((d >> 3) ^ (t & 7)) << 3) + (d & 7)] = f2bf(v);
          } else {                            // Vt: [bh][d][t], XOR-(d&7) per 64-chunk
            size_t o = ((size_t)(b * 16 + h) * 64 + d) * 1024 + (t & ~63) +
                       ((((t >> 3) & 7) ^ (d & 7)) << 3) + (t & 7);
            outUp[o] = f2bf(v);
          }
        } else if constexpr (EPI == EPI_BF16) {
          outUp[(size_t)row * N + col] = f2bf(v);
        } else if constexpr (EPI == EPI_SILU_BF16) {
          float z = v + bias[col];
          outUp[(size_t)row * N + col] = f2bf(z / (1.f + __expf(-z)));
        } else {  // EPI_BIAS_F32
          outF[(size_t)row * N + col] = v + bias[col];
        }
      }
    }
  }
}

// ---------------------------------------------------------------------------
// GEMM 8-wave BK=64 (tail GEMMs): 128x128 tile, 512 thr, 64KB LDS dbuf.
// 16 k-steps (vs 32): half the barrier+vmcnt(0) drains, each amortized over
// 16 MFMA + 12 ds_read_b128 per wave.  LDS row = 128B (8 x 16B slots); global
// 16B-block g stored at slot g ^ (row & 7); read slot = (kk*4+lq) ^ (lr&7).
// ---------------------------------------------------------------------------
template <int EPI>
__global__ __launch_bounds__(512) void gemm_bt8(
    const u16* __restrict__ A, int lda,
    const u16* __restrict__ W, int ldw,
    int M, int N, int K,
    float* __restrict__ outF, u16* __restrict__ outU,
    const float* __restrict__ bias) {
  __shared__ u16 As[2][128 * 64];   // 2 x 16 KB
  __shared__ u16 Bs[2][128 * 64];   // 2 x 16 KB
  int tid = threadIdx.x;
  int l = tid & 63, w = tid >> 6;                  // 8 waves
  int wr = w >> 2, wc = w & 3, lr = l & 15, lq = l >> 4;

  int fid = blockIdx.y * 8 + blockIdx.x;
  int swz = (fid & 7) * 64 + (fid >> 3);
  int m0 = (swz >> 3) * 128, n0 = (swz & 7) * 128;

  f32x4 acc[4][2];
#pragma unroll
  for (int i = 0; i < 4; i++)
#pragma unroll
    for (int j = 0; j < 2; j++) acc[i][j] = zero4();

  auto stage = [&](const u16* src, int ld, int r0, int k0, u16* lds) {
#pragma unroll
    for (int j = 0; j < 2; ++j) {
      int seg = j * 512 + tid;             // 1024 segs x 16B = 16 KB
      int row = seg >> 3, sp = seg & 7;
      const u16* g = src + (size_t)(r0 + row) * ld + k0 +
                     ((sp ^ (row & 7)) << 3);
      GLL16(g, lds + seg * 8);
    }
  };

  int nk = K >> 6;                          // 16
  stage(A, lda, m0, 0, As[0]);
  stage(W, ldw, n0, 0, Bs[0]);
  for (int kt = 0; kt < nk; ++kt) {
    __syncthreads();
    if (kt + 1 < nk) {
      stage(A, lda, m0, (kt + 1) << 6, As[(kt + 1) & 1]);
      stage(W, ldw, n0, (kt + 1) << 6, Bs[(kt + 1) & 1]);
    }
    const u16* Ab = As[kt & 1];
    const u16* Bb = Bs[kt & 1];
    bf16x8 af[4][2], bw[2][2];
#pragma unroll
    for (int kk = 0; kk < 2; kk++) {
      int slot = ((kk * 4 + lq) ^ (lr & 7)) << 3;
#pragma unroll
      for (int mi = 0; mi < 4; mi++)
        af[mi][kk] = *(const bf16x8*)&Ab[(wr * 64 + mi * 16 + lr) * 64 + slot];
#pragma unroll
      for (int ni = 0; ni < 2; ni++)
        bw[ni][kk] = *(const bf16x8*)&Bb[(wc * 32 + ni * 16 + lr) * 64 + slot];
    }
#pragma unroll
    for (int kk = 0; kk < 2; kk++)
#pragma unroll
      for (int mi = 0; mi < 4; mi++)
#pragma unroll
        for (int ni = 0; ni < 2; ni++)
          acc[mi][ni] = __builtin_amdgcn_mfma_f32_16x16x32_bf16(
              af[mi][kk], bw[ni][kk], acc[mi][ni], 0, 0, 0);
  }

#pragma unroll
  for (int mi = 0; mi < 4; mi++) {
#pragma unroll
    for (int ni = 0; ni < 2; ni++) {
      int col = n0 + wc * 32 + ni * 16 + lr;
#pragma unroll
      for (int r = 0; r < 4; r++) {
        int row = m0 + wr * 64 + mi * 16 + lq * 4 + r;
        float v = acc[mi][ni][r];
        if constexpr (EPI == EPI_BF16) {
          outU[(size_t)row * N + col] = f2bf(v);
        } else if constexpr (EPI == EPI_SILU_BF16) {
          float z = v + bias[col];
          outU[(size_t)row * N + col] = f2bf(z / (1.f + __expf(-z)));
        } else {  // EPI_BIAS_F32
          outF[(size_t)row * N + col] = v + bias[col];
        }
      }
    }
  }
}

// ---------------------------------------------------------------------------
// Attention: two-pass recompute, 8 waves x 16 q-rows (512 thr), dbuf K/V.
// Grid (1024): qi = bid>>7, bh = (bid&7)*16 + ((bid>>3)&15)  (XCD-resident).
// Q2 [bh][t][64] plain; K2 [bh][t][64] XOR-(t&7); Vt [bh][d][1024] XOR-(d&7).
// LDS 50 KB: Ks 16K + Vs 16K + Ps 18K.
// ---------------------------------------------------------------------------
__global__ __launch_bounds__(512) void attn_kernel(
    const u16* __restrict__ Q2, const u16* __restrict__ K2,
    const u16* __restrict__ Vt, const float* __restrict__ alphap,
    float* __restrict__ masked_out, u16* __restrict__ attn_out) {
  __shared__ __align__(16) u16 Ks[2][4096];        // 16 KB
  __shared__ __align__(16) u16 Vs[2][4096];        // 16 KB
  __shared__ __align__(16) u16 Ps[8][16 * 72];     // 18 KB

  int tid = threadIdx.x;
  int l = tid & 63, w = tid >> 6, lr = l & 15, lq = l >> 4;   // w in 0..7

  int bid = blockIdx.x;
  int qi  = bid >> 7;                              // 0..7 q-chunk (128 rows)
  int bh  = (bid & 7) * 16 + ((bid >> 3) & 15);    // 0..127, XCD-resident
  int h = bh & 15, b = bh >> 4;
  int q0 = qi * 128;

  const u16* Qb = Q2 + (size_t)bh * 1024 * 64;
  const u16* Kb = K2 + (size_t)bh * 1024 * 64;
  const u16* Vb = Vt + (size_t)bh * 64 * 1024;
  float alpha = alphap[0];
  int qw = q0 + w * 16;                            // this wave's 16 q-rows

  auto stageK = [&](int kc, u16* dst) {            // 8 KB, 512 thr x 16B
    int seg = tid;
    GLL16(Kb + (size_t)kc * 4096 + seg * 8, dst + seg * 8);
  };
  auto stageV = [&](int kc, u16* dst) {            // row d = seg>>3, part seg&7
    int seg = tid;
    GLL16(Vb + (size_t)(seg >> 3) * 1024 + kc * 64 + (seg & 7) * 8, dst + seg * 8);
  };

  // Q fragments in registers (A-frag: row = lr, k = kt*32 + lq*8 + j)
  bf16x8 qf[2];
#pragma unroll
  for (int kt = 0; kt < 2; kt++)
    qf[kt] = *(const bf16x8*)(Qb + (size_t)(qw + lr) * 64 + kt * 32 + lq * 8);

  float s1[4] = {0.f, 0.f, 0.f, 0.f};

  // ---- pass 1 ----
  stageK(0, Ks[0]);
  for (int kc = 0; kc < 16; ++kc) {
    __syncthreads();                            // drains stage(kc); prev reads done
    if (kc + 1 < 16) stageK(kc + 1, Ks[(kc + 1) & 1]);
    const u16* Kc = Ks[kc & 1];
    f32x4 acc[4];
#pragma unroll
    for (int ni = 0; ni < 4; ni++) acc[ni] = zero4();
    __builtin_amdgcn_s_setprio(1);              // T5
#pragma unroll
    for (int ni = 0; ni < 4; ++ni) {
      int t = ni * 16 + lr;
      bf16x8 k0 = *(const bf16x8*)&Kc[t * 64 + (((0 + lq) ^ (lr & 7)) << 3)];
      bf16x8 k1 = *(const bf16x8*)&Kc[t * 64 + (((4 + lq) ^ (lr & 7)) << 3)];
      acc[ni] = __builtin_amdgcn_mfma_f32_16x16x32_bf16(qf[0], k0, acc[ni], 0, 0, 0);
      acc[ni] = __builtin_amdgcn_mfma_f32_16x16x32_bf16(qf[1], k1, acc[ni], 0, 0, 0);
    }
    __builtin_amdgcn_s_setprio(0);
#pragma unroll
    for (int ni = 0; ni < 4; ni++)
#pragma unroll
      for (int r = 0; r < 4; r++)
        s1[r] += __expf(acc[ni][r] * 0.125f);
  }
#pragma unroll
  for (int r = 0; r < 4; r++) {
    float v = s1[r];
    v += __shfl_xor(v, 1); v += __shfl_xor(v, 2);
    v += __shfl_xor(v, 4); v += __shfl_xor(v, 8);
    s1[r] = 1.0f / v;
  }

  // ---- pass 2 ----
  float s2[4] = {0.f, 0.f, 0.f, 0.f};
  f32x4 oacc[4];
#pragma unroll
  for (int dg = 0; dg < 4; dg++) oacc[dg] = zero4();

  stageK(0, Ks[0]);                             // Ks[0] reads done by kc=15 sync
  stageV(0, Vs[0]);
  for (int kc = 0; kc < 16; ++kc) {
    // Counted-vmcnt barrier: per kc the wave issues 2 staging loads then 16
    // masked stores.  vmcnt(16) at the barrier completes the loads (and all
    // older stores); the 16 newest stores drain under the next iteration.
    if (kc == 0) {
      asm volatile("s_waitcnt vmcnt(0) lgkmcnt(0)" ::: "memory");
    } else {
      asm volatile("s_waitcnt vmcnt(16) lgkmcnt(0)" ::: "memory");
    }
    __builtin_amdgcn_s_barrier();
    __builtin_amdgcn_sched_barrier(0);
    if (kc + 1 < 16) {
      stageK(kc + 1, Ks[(kc + 1) & 1]);
      stageV(kc + 1, Vs[(kc + 1) & 1]);
    }
    const u16* Kc = Ks[kc & 1];
    const u16* Vc = Vs[kc & 1];

    f32x4 acc[4];
#pragma unroll
    for (int ni = 0; ni < 4; ni++) acc[ni] = zero4();
    __builtin_amdgcn_s_setprio(1);              // T5
#pragma unroll
    for (int ni = 0; ni < 4; ++ni) {
      int t = ni * 16 + lr;
      bf16x8 k0 = *(const bf16x8*)&Kc[t * 64 + (((0 + lq) ^ (lr & 7)) << 3)];
      bf16x8 k1 = *(const bf16x8*)&Kc[t * 64 + (((4 + lq) ^ (lr & 7)) << 3)];
      acc[ni] = __builtin_amdgcn_mfma_f32_16x16x32_bf16(qf[0], k0, acc[ni], 0, 0, 0);
      acc[ni] = __builtin_amdgcn_mfma_f32_16x16x32_bf16(qf[1], k1, acc[ni], 0, 0, 0);
    }
    __builtin_amdgcn_s_setprio(0);

#pragma unroll
    for (int ni = 0; ni < 4; ni++) {
#pragma unroll
      for (int r = 0; r < 4; r++) {
        float e = __expf(acc[ni][r] * 0.125f);
        float a = e * s1[r];
        a = (a >= alpha) ? a : 0.0f;
        size_t row = (size_t)bh * 1024 + qw + lq * 4 + r;
        masked_out[row * 1024 + kc * 64 + ni * 16 + lr] = a;
        float p = __expf(a);
        s2[r] += p;
        Ps[w][(lq * 4 + r) * 72 + ni * 16 + lr] = f2bf(p);
      }
    }
    // wave-local Ps handoff: Ps[w] is written and read only by wave w.
    asm volatile("s_waitcnt lgkmcnt(0)" ::: "memory");

    bf16x8 pf[2];
#pragma unroll
    for (int kt = 0; kt < 2; kt++)
      pf[kt] = *(const bf16x8*)&Ps[w][lr * 72 + kt * 32 + lq * 8];
    __builtin_amdgcn_s_setprio(1);              // T5
#pragma unroll
    for (int dg = 0; dg < 4; dg++) {
      int d = dg * 16 + lr;
      bf16x8 v0 = *(const bf16x8*)&Vc[d * 64 + (((0 + lq) ^ (lr & 7)) << 3)];
      bf16x8 v1 = *(const bf16x8*)&Vc[d * 64 + (((4 + lq) ^ (lr & 7)) << 3)];
      oacc[dg] = __builtin_amdgcn_mfma_f32_16x16x32_bf16(pf[0], v0, oacc[dg], 0, 0, 0);
      oacc[dg] = __builtin_amdgcn_mfma_f32_16x16x32_bf16(pf[1], v1, oacc[dg], 0, 0, 0);
    }
    __builtin_amdgcn_s_setprio(0);
  }

#pragma unroll
  for (int r = 0; r < 4; r++) {
    float v = s2[r];
    v += __shfl_xor(v, 1); v += __shfl_xor(v, 2);
    v += __shfl_xor(v, 4); v += __shfl_xor(v, 8);
    s2[r] = 1.0f / v;
  }
#pragma unroll
  for (int dg = 0; dg < 4; dg++)
#pragma unroll
    for (int r = 0; r < 4; r++) {
      int q = qw + lq * 4 + r;
      attn_out[(size_t)(b * 1024 + q) * 1024 + h * 64 + dg * 16 + lr] =
          f2bf(oacc[dg][r] * s2[r]);
    }
}

// ---------------------------------------------------------------------------
// LayerNorm over D=1024: y = (A + bf2f(Bv) - mu)*rsqrt(var+eps)*g + beta
// ---------------------------------------------------------------------------
__global__ __launch_bounds__(256) void ln_kernel(
    const float* __restrict__ A, const u16* __restrict__ Bv,
    const float* __restrict__ g, const float* __restrict__ beta,
    float* __restrict__ outF, u16* __restrict__ outB) {
  __shared__ float red[4];
  int row = blockIdx.x, t = threadIdx.x;
  const float* pa = A + (size_t)row * 1024;
  const u16* pb = Bv + (size_t)row * 1024;
  float v[4];
  float s = 0.f;
#pragma unroll
  for (int i = 0; i < 4; i++) {
    int c = t + 256 * i;
    v[i] = pa[c] + bf2f(pb[c]);
    s += v[i];
  }
#pragma unroll
  for (int off = 1; off < 64; off <<= 1) s += __shfl_xor(s, off);
  if ((t & 63) == 0) red[t >> 6] = s;
  __syncthreads();
  s = red[0] + red[1] + red[2] + red[3];
  float mu = s * 0.0009765625f;
  float q = 0.f;
#pragma unroll
  for (int i = 0; i < 4; i++) { float d = v[i] - mu; q += d * d; }
  __syncthreads();
#pragma unroll
  for (int off = 1; off < 64; off <<= 1) q += __shfl_xor(q, off);
  if ((t & 63) == 0) red[t >> 6] = q;
  __syncthreads();
  q = red[0] + red[1] + red[2] + red[3];
  float rs = rsqrtf(q * 0.0009765625f + 1e-5f);
#pragma unroll
  for (int i = 0; i < 4; i++) {
    int c = t + 256 * i;
    float y = (v[i] - mu) * rs * g[c] + beta[c];
    if (outF) outF[(size_t)row * 1024 + c] = y;
    if (outB) outB[(size_t)row * 1024 + c] = f2bf(y);
  }
}

// ---------------------------------------------------------------------------
// Workspace (bytes), aliased by lifetime.
// ---------------------------------------------------------------------------
#define WS_BASEB   0            // [8192][1024] u16 = 16 MB (dead after QKV gemm)
#define WS_FUSB    16777216     // 16 MB (dead after QKV gemm)
#define WS_W       33554432     // 7 x [1024][1024] u16 = 14 MB
#define WS_QKV     48234496     // Q2 16MB | K2 16MB | Vt 16MB (dead after attn)
#define WS_ATTNO   98566144     // [8192][1024] u16 = 16 MB (dead after O gemm)
#define WS_X       115343360    // [8192][1024] f32 = 32 MB (ends 148897792)
#define WS_OB      WS_FUSB                  // [8192][1024] u16 (fusb dead)
#define WS_XB      WS_BASEB                 // [8192][1024] u16 (baseb dead)
#define WS_H1      WS_ATTNO                 // alias (attno dead)
#define WS_FFB     WS_QKV                   // alias Q2 (dead after attn)
#define WS_YB      (WS_QKV + 16777216)      // alias K2 (dead)

extern "C" void kernel_launch(void* const* d_in, const int* in_sizes, int n_in,
                              void* d_out, int out_size, void* d_ws, size_t ws_size,
                              hipStream_t stream) {
  const float* base   = (const float*)d_in[0];
  const float* fusion = (const float*)d_in[1];
  const float* Wq     = (const float*)d_in[2];
  const float* Wk     = (const float*)d_in[3];
  const float* Wv     = (const float*)d_in[4];
  const float* Wo     = (const float*)d_in[5];
  const float* g1     = (const float*)d_in[6];
  const float* b1     = (const float*)d_in[7];
  const float* g2     = (const float*)d_in[8];
  const float* b2     = (const float*)d_in[9];
  const float* fc1w   = (const float*)d_in[10];
  const float* fc1b   = (const float*)d_in[11];
  const float* fc2w   = (const float*)d_in[12];
  const float* fc2b   = (const float*)d_in[13];
  const float* rw     = (const float*)d_in[14];
  const float* rb     = (const float*)d_in[15];
  const float* alphap = (const float*)d_in[16];

  char* ws = (char*)d_ws;
  u16* baseb  = (u16*)(ws + WS_BASEB);
  u16* fusb   = (u16*)(ws + WS_FUSB);
  u16* wall   = (u16*)(ws + WS_W);        // wq|wk|wv|wo|fc1|fc2|rw
  u16* Q2     = (u16*)(ws + WS_QKV);      // K2 = Q2+8388608, Vt = Q2+16777216 (elems)
  u16* attno  = (u16*)(ws + WS_ATTNO);
  u16* obufb  = (u16*)(ws + WS_OB);
  float* x    = (float*)(ws + WS_X);
  u16* xb     = (u16*)(ws + WS_XB);
  u16* h1     = (u16*)(ws + WS_H1);
  u16* ffb    = (u16*)(ws + WS_FFB);
  u16* yb     = (u16*)(ws + WS_YB);

  float* final_out  = (float*)d_out;
  float* masked_out = final_out + 8388608;

  // 1. pack (vec4)
  pack_act<<<dim3(8192, 2), 256, 0, stream>>>(base, fusion, baseb, fusb);
  pack_w<<<dim3(1024, 7), 256, 0, stream>>>(Wq, Wk, Wv, Wo, fc1w, fc2w, rw, wall);

  dim3 gg(8, 64);

  // 2. QKV merged (z: 0=Q plain, 1=K swizzled, 2=Vt) - 4-wave BK=32 kernel
  gemm_bt<EPI_QKV><<<dim3(8, 64, 3), 256, 0, stream>>>(
      baseb, 1024, wall, 1024, 8192, 1024, 1024, nullptr, Q2, nullptr, fusb);

  // 3. attention (flat grid, XCD-swizzled inside, 8 waves)
  attn_kernel<<<dim3(1024), 512, 0, stream>>>(
      Q2, Q2 + 8388608, Q2 + 16777216, alphap, masked_out, attno);

  // 4. output proj (bf16 out, 8-wave BK=64) + LN1
  gemm_bt8<EPI_BF16><<<gg, 512, 0, stream>>>(attno, 1024, wall + 3 * 1048576, 1024,
                                             8192, 1024, 1024, nullptr, obufb, nullptr);
  ln_kernel<<<8192, 256, 0, stream>>>(base, obufb, g1, b1, x, xb);

  // 5. FFN + LN2 (8-wave BK=64)
  gemm_bt8<EPI_SILU_BF16><<<gg, 512, 0, stream>>>(xb, 1024, wall + 4 * 1048576, 1024,
                                                  8192, 1024, 1024, nullptr, h1, fc1b);
  gemm_bt8<EPI_SILU_BF16><<<gg, 512, 0, stream>>>(h1, 1024, wall + 5 * 1048576, 1024,
                                                  8192, 1024, 1024, nullptr, ffb, fc2b);
  ln_kernel<<<8192, 256, 0, stream>>>(x, ffb, g2, b2, nullptr, yb);

  // 6. final projection (8-wave BK=64)
  gemm_bt8<EPI_BIAS_F32><<<gg, 512, 0, stream>>>(yb, 1024, wall + 6 * 1048576, 1024,
                                                 8192, 1024, 1024, final_out, nullptr, rb);
}